// Round 5
// baseline (452.962 us; speedup 1.0000x reference)
//
#include <hip/hip_runtime.h>
#include <hip/hip_bf16.h>

#define HID 64
#define MROWS 1140   // C(20,3) rows per graph at level 3
#define PAD1 20      // level-1 in-degree <= 19
#define PAD2 40      // level-2 in-degree <= 38 (2 shared-elem choices x <=19 partners)
#define PAD3 60      // level-3 in-degree <= 54 (3 shared-pair choices x <=18 third-elems)

typedef __hip_bfloat16  bf16;
typedef __hip_bfloat162 bf162;
typedef unsigned short  u16;
typedef __attribute__((ext_vector_type(8))) short bf8v;
typedef __attribute__((ext_vector_type(4))) float f4v;
typedef __attribute__((ext_vector_type(4))) unsigned int u4v;
__device__ __forceinline__ float bl(bf16 h) { return __bfloat162float(h); }

// ======== padded CSR build: zero + fill (no hist/scan needed) ========
// csrc stores GRAPH-LOCAL ids as u16 (max row/graph = 1140 < 65536).
__global__ void zero_k(int* p, int n) {
    int i = blockIdx.x * 256 + threadIdx.x;
    if (i < n) p[i] = 0;
}

__global__ void fillp_k(const int* e1, int E1, int* c1, u16* s1, int p1, int P1_,
                        const int* e2, int E2, int* c2, u16* s2, int p2, int P2_,
                        const int* e3, int E3, int* c3, u16* s3, int p3, int P3_,
                        int nb1, int nb2) {
    int b = blockIdx.x;
    const int* edges; int E; int* cur; u16* csrc; int pad; int P; int lb;
    if (b < nb1)            { edges = e1; E = E1; cur = c1; csrc = s1; pad = p1; P = P1_; lb = b; }
    else if (b < nb1 + nb2) { edges = e2; E = E2; cur = c2; csrc = s2; pad = p2; P = P2_; lb = b - nb1; }
    else                    { edges = e3; E = E3; cur = c3; csrc = s3; pad = p3; P = P3_; lb = b - nb1 - nb2; }
    int e = lb * 256 + threadIdx.x;
    if (e >= E) return;
    int d = edges[E + e];
    int slot = atomicAdd(&cur[d], 1);
    if (slot < pad) csrc[(size_t)d * pad + slot] = (u16)(edges[e] % P);   // local id
}

// ======== level-1 GNN + segsum + the 5 table projections (h stays in LDS) ========
// 1024 threads: thread t -> (row t>>6, col t&63); threads t<256 also row 16+(t>>6).
// Weight staging is COALESCED (W[i] row-major) into +1-padded LDS (stride K+1 ==
// 1 mod 32 -> conflict-free reads).
struct TJob { const float* Wa; const float* Wb; bf162* o; int ldw; int coloff; };
struct TJobs5 { TJob j[5]; };

__global__ __launch_bounds__(1024)
void level1T_k(const float* __restrict__ x,
               const int* __restrict__ cnt1, const u16* __restrict__ csrc1,
               const float* __restrict__ W10, const float* __restrict__ W20,
               const float* __restrict__ W11, const float* __restrict__ W21,
               const float* __restrict__ W12, const float* __restrict__ W22,
               TJobs5 jobs, float* __restrict__ comb, int nper) {
    __shared__ float hbuf[20][64];
    __shared__ float mbuf[20][64];
    __shared__ float wl1[64 * 65];
    __shared__ float wl2[64 * 65];
    int g = blockIdx.x, t = threadIdx.x;
    int base = g * nper;
    int col = t & 63, r0 = t >> 6;
    bool has2 = r0 < 4; int r1 = 16 + r0;

    if (t < 640) hbuf[t >> 5][t & 31] = x[(size_t)base * 32 + t];

    const float* W1s[3] = {W10, W11, W12};
    const float* W2s[3] = {W20, W21, W22};
#pragma unroll 1
    for (int l = 0; l < 3; ++l) {
        const int K = (l == 0) ? 32 : 64;
        const int LD = K + 1;
        const float* W1 = W1s[l];
        const float* W2 = W2s[l];
        __syncthreads();
        // coalesced stage: W row-major [64][K]
        for (int i = t; i < K * 64; i += 1024) {
            int c = i / K, k = i - c * K;
            wl1[c * LD + k] = W1[i];
            wl2[c * LD + k] = W2[i];
        }
        __syncthreads();
        float az0 = 0.f, am0 = 0.f, az1 = 0.f, am1 = 0.f;
        const float* wr1 = wl1 + col * LD;
        const float* wr2 = wl2 + col * LD;
        for (int k = 0; k < K; ++k) {
            float w1v = wr1[k], w2v = wr2[k];
            float h0v = hbuf[r0][k];
            az0 = fmaf(h0v, w1v, az0); am0 = fmaf(h0v, w2v, am0);
            if (has2) {
                float h1v = hbuf[r1][k];
                az1 = fmaf(h1v, w1v, az1); am1 = fmaf(h1v, w2v, am1);
            }
        }
        mbuf[r0][col] = am0;
        if (has2) mbuf[r1][col] = am1;
        __syncthreads();
        {
            int cnt = cnt1[base + r0];
            const u16* cs = csrc1 + (size_t)(base + r0) * PAD1;
            float acc = az0;
            for (int k = 0; k < cnt; ++k) acc += mbuf[cs[k]][col];
            hbuf[r0][col] = fmaxf(acc, 0.f);
        }
        if (has2) {
            int cnt = cnt1[base + r1];
            const u16* cs = csrc1 + (size_t)(base + r1) * PAD1;
            float acc = az1;
            for (int k = 0; k < cnt; ++k) acc += mbuf[cs[k]][col];
            hbuf[r1][col] = fmaxf(acc, 0.f);
        }
    }
    __syncthreads();
    if (t < 64) {
        float s = 0.f;
#pragma unroll
        for (int r = 0; r < 20; ++r) s += hbuf[r][t];
        comb[g * 192 + t] = s;   // level-1 embedding, cols 0..63
    }
    // ---- 5 table projections (bf162 interleaved outputs)
#pragma unroll 1
    for (int jj = 0; jj < 5; ++jj) {
        const float* Wa = jobs.j[jj].Wa;
        const float* Wb = jobs.j[jj].Wb;
        bf162* o = jobs.j[jj].o;
        int ldw = jobs.j[jj].ldw, coloff = jobs.j[jj].coloff;
        for (int i = t; i < 4096; i += 1024) {
            int c = i >> 6, k = i & 63;
            wl1[c * 65 + k] = Wa[c * ldw + coloff + k];   // 64-float coalesced runs
            wl2[c * 65 + k] = Wb[c * ldw + coloff + k];
        }
        __syncthreads();
        const float* wr1 = wl1 + col * 65;
        const float* wr2 = wl2 + col * 65;
        {
            float sx = 0.f, sy = 0.f, sx1 = 0.f, sy1 = 0.f;
            for (int k = 0; k < 64; ++k) {
                float w1v = wr1[k], w2v = wr2[k];
                float h0v = hbuf[r0][k];
                sx = fmaf(h0v, w1v, sx); sy = fmaf(h0v, w2v, sy);
                if (has2) {
                    float h1v = hbuf[r1][k];
                    sx1 = fmaf(h1v, w1v, sx1); sy1 = fmaf(h1v, w2v, sy1);
                }
            }
            bf162 v; v.x = __float2bfloat16(sx); v.y = __float2bfloat16(sy);
            o[(size_t)(g * 20 + r0) * 64 + col] = v;
            if (has2) {
                bf162 v1; v1.x = __float2bfloat16(sx1); v1.y = __float2bfloat16(sy1);
                o[(size_t)(g * 20 + r1) * 64 + col] = v1;
            }
        }
        __syncthreads();
    }
}

// ======== FUSED levels 2+3, split across (graph, half) with rt-granular ownership ====
struct FJob {
    const bf162 *tA, *tB, *tC;      // projected node tables (tC null => level 2)
    const int *ga, *gb, *gc;        // global node ids per row
    const float *iso;               // level3: float4 one-hot; level2: float
    const float *wc1, *wc2; int ldw, isoC;
    const float *Wl1, *Wl2;         // layer-1 weights [64][64]
    const u16 *csrc; const int *cnt; int pad;   // padded CSR (local ids)
    bf16 *zc; bf16 *m1g;            // layer-1 preact + message scratch (bf16 [n][64])
    int P, ntiles, comboff;
};

__device__ __forceinline__ int msw(int row, int ch) {
    return (row << 6) + ((ch ^ (row & 7)) << 3);
}
__device__ __forceinline__ void accu4(u4v v, float* f) {
#pragma unroll
    for (int i = 0; i < 4; ++i) {
        f[2 * i]     += __uint_as_float(v[i] << 16);
        f[2 * i + 1] += __uint_as_float(v[i] & 0xffff0000u);
    }
}
__device__ __forceinline__ void accxy4(u4v v, float* zx, float* zy) {
#pragma unroll
    for (int i = 0; i < 4; ++i) {
        zx[i] += __uint_as_float(v[i] << 16);
        zy[i] += __uint_as_float(v[i] & 0xffff0000u);
    }
}
__device__ __forceinline__ bf8v pack8(const float* f) {
    bf16 tmp[8];
#pragma unroll
    for (int e = 0; e < 8; ++e) tmp[e] = __float2bfloat16(f[e]);
    bf8v r; __builtin_memcpy(&r, tmp, 16); return r;
}
__device__ __forceinline__ bf8v pack8relu(const float* f) {
    bf16 tmp[8];
#pragma unroll
    for (int e = 0; e < 8; ++e) tmp[e] = __float2bfloat16(fmaxf(f[e], 0.f));
    bf8v r; __builtin_memcpy(&r, tmp, 16); return r;
}
__device__ __forceinline__ u4v asu4(bf8v v) { u4v r; __builtin_memcpy(&r, &v, 16); return r; }
__device__ __forceinline__ void hsacc(const bf162* tb, int nd, int c4, float* zx, float* zy) {
    u4v v0 = *(const u4v*)(tb + (nd << 6) + (((c4    ) ^ (nd & 15)) << 2));
    u4v v1 = *(const u4v*)(tb + (nd << 6) + (((c4 + 1) ^ (nd & 15)) << 2));
    accxy4(v0, zx, zy);
    accxy4(v1, zx + 4, zy + 4);
}
__device__ __forceinline__ void hsaccY(const bf162* tb, int nd, int c4, float* zy) {
    u4v v0 = *(const u4v*)(tb + (nd << 6) + (((c4    ) ^ (nd & 15)) << 2));
    u4v v1 = *(const u4v*)(tb + (nd << 6) + (((c4 + 1) ^ (nd & 15)) << 2));
#pragma unroll
    for (int i = 0; i < 4; ++i) {
        zy[i]     += __uint_as_float(v0[i] & 0xffff0000u);
        zy[4 + i] += __uint_as_float(v1[i] & 0xffff0000u);
    }
}
__device__ __forceinline__ void naccum(const bf16* mL, int nbr, int quad, float* acc) {
    u4v v0 = *(const u4v*)(mL + msw(nbr, quad));
    u4v v1 = *(const u4v*)(mL + msw(nbr, quad + 4));
    accu4(v0, acc); accu4(v1, acc + 8);
}

__device__ __forceinline__ void run_k1(const FJob& jb, int g, int h,
                                       bf16* mLDS, bf16* wstage) {
    int t = threadIdx.x;
    const int P = jb.P, nT = jb.tC ? 3 : 2;
    const int gbase = g * P, nb20 = g * 20;
    int lane = t & 63, wv = t >> 6, quad = lane >> 4, m16 = lane & 15;

    // ---- P0: stage projected node tables (swizzled) + iso-weight table
    bf162* hsA = (bf162*)wstage;
    const bf162* hsB = hsA + 1280;
    const bf162* hsC = hsA + 2560;
    for (int i = t; i < nT * 1280; i += 1024) {
        int table = i / 1280, rem = i - table * 1280;
        int node = rem >> 6, f = rem & 63, c4 = f >> 2;
        const bf162* src = (table == 0) ? jb.tA : (table == 1) ? jb.tB : jb.tC;
        hsA[table * 1280 + (node << 6) + ((c4 ^ (node & 15)) << 2) + (f & 3)] =
            src[(size_t)g * 1280 + rem];
    }
    float* wcT = (float*)(wstage + 7680);   // [2 mats][4 c][64 f]
    if (t < 512) {
        int mat = t >> 8, c = (t >> 6) & 3, f = t & 63;
        const float* W = mat ? jb.wc2 : jb.wc1;
        wcT[mat * 256 + c * 64 + f] = (c < jb.isoC) ? W[f * jb.ldw + c] : 0.f;
    }
    __syncthreads();

    // ---- P1: layer-0 gather -> z (regs, owned rt only) + m0 (LDS, all rows)
    bf8v z8[3][2];
#pragma unroll
    for (int k = 0; k < 3; ++k) {
        int tile = wv + k * 16;
        if (tile >= jb.ntiles) continue;
#pragma unroll
        for (int rt = 0; rt < 2; ++rt) {
            bool own = (rt == h);
            int row = tile * 32 + rt * 16 + m16;
            float zx[16], zy[16];
#pragma unroll
            for (int j = 0; j < 16; ++j) { zx[j] = 0.f; zy[j] = 0.f; }
            if (row < P) {
                size_t gr = (size_t)gbase + row;
                int na = jb.ga[gr] - nb20;
                int nb = jb.gb[gr] - nb20;
                int nc = 0;
                const float* w1r; const float* w2r; float isw;
                if (nT == 3) {
                    nc = jb.gc[gr] - nb20;
                    float4 iv = ((const float4*)jb.iso)[gr];   // one-hot eye(4)[ec]
                    int ec = (int)(iv.y + 2.f * iv.z + 3.f * iv.w + 0.5f);
                    w1r = wcT + ec * 64; w2r = wcT + 256 + ec * 64; isw = 1.f;
                } else {
                    w1r = wcT; w2r = wcT + 256; isw = jb.iso[gr];
                }
#pragma unroll
                for (int kt = 0; kt < 2; ++kt) {
                    int c4 = kt * 8 + quad * 2;
                    int f0 = kt * 32 + quad * 8;
                    if (own) {
                        hsacc(hsA, na, c4, zx + kt * 8, zy + kt * 8);
                        hsacc(hsB, nb, c4, zx + kt * 8, zy + kt * 8);
                        if (nT == 3) hsacc(hsC, nc, c4, zx + kt * 8, zy + kt * 8);
#pragma unroll
                        for (int e = 0; e < 8; ++e)
                            zx[kt * 8 + e] = fmaf(isw, w1r[f0 + e], zx[kt * 8 + e]);
                    } else {
                        hsaccY(hsA, na, c4, zy + kt * 8);
                        hsaccY(hsB, nb, c4, zy + kt * 8);
                        if (nT == 3) hsaccY(hsC, nc, c4, zy + kt * 8);
                    }
#pragma unroll
                    for (int e = 0; e < 8; ++e)
                        zy[kt * 8 + e] = fmaf(isw, w2r[f0 + e], zy[kt * 8 + e]);
                }
                *(bf8v*)(mLDS + msw(row, quad))     = pack8(zy);
                *(bf8v*)(mLDS + msw(row, quad + 4)) = pack8(zy + 8);
            }
            if (own) { z8[k][0] = pack8(zx); z8[k][1] = pack8(zx + 8); }
        }
    }
    __syncthreads();

    // ---- P2: stage layer-1 W frags (frag-major) + neighsum-1 for owned rows
    for (int i = t; i < 8192; i += 1024) {
        int e = i & 7, mm = (i >> 3) & 15, qq = (i >> 7) & 3;
        int kk = (i >> 9) & 1, mat = (i >> 10) & 1, nn = i >> 11;
        const float* W = mat ? jb.Wl2 : jb.Wl1;
        wstage[i] = __float2bfloat16(W[(nn * 16 + mm) * HID + kk * 32 + qq * 8 + e]);
    }
#pragma unroll
    for (int k = 0; k < 3; ++k) {
        int tile = wv + k * 16;
        if (tile >= jb.ntiles) continue;
        int row = tile * 32 + h * 16 + m16;
        float acc[16];
#pragma unroll
        for (int j = 0; j < 16; ++j) acc[j] = 0.f;
        accu4(asu4(z8[k][0]), acc);
        accu4(asu4(z8[k][1]), acc + 8);
        if (row < P) {
            size_t gr = (size_t)gbase + row;
            int cnt = jb.cnt[gr];
            const u16* cs = jb.csrc + gr * (size_t)jb.pad;
            int kk = 0;
            for (; kk + 4 <= cnt; kk += 4) {
                int n0 = cs[kk], n1 = cs[kk + 1], n2 = cs[kk + 2], n3 = cs[kk + 3];
                naccum(mLDS, n0, quad, acc); naccum(mLDS, n1, quad, acc);
                naccum(mLDS, n2, quad, acc); naccum(mLDS, n3, quad, acc);
            }
            for (; kk < cnt; ++kk) naccum(mLDS, cs[kk], quad, acc);
        }
        z8[k][0] = pack8relu(acc);
        z8[k][1] = pack8relu(acc + 8);
    }
    __syncthreads();

    // ---- P3: dual MFMA GEMM (owned rt only). zc + m1 -> GLOBAL.
#pragma unroll
    for (int k = 0; k < 3; ++k) {
        int tile = wv + k * 16;
        if (tile >= jb.ntiles) continue;
        int j0 = tile * 32;
#pragma unroll
        for (int n = 0; n < 4; ++n) {
            const bf8v b1k0 = *(const bf8v*)(wstage + ((((n*2+0)*2+0)*4+quad)*16+m16)*8);
            const bf8v b1k1 = *(const bf8v*)(wstage + ((((n*2+0)*2+1)*4+quad)*16+m16)*8);
            const bf8v b2k0 = *(const bf8v*)(wstage + ((((n*2+1)*2+0)*4+quad)*16+m16)*8);
            const bf8v b2k1 = *(const bf8v*)(wstage + ((((n*2+1)*2+1)*4+quad)*16+m16)*8);
            f4v acca = {0.f, 0.f, 0.f, 0.f};
            f4v accb = {0.f, 0.f, 0.f, 0.f};
            acca = __builtin_amdgcn_mfma_f32_16x16x32_bf16(z8[k][0], b1k0, acca, 0, 0, 0);
            acca = __builtin_amdgcn_mfma_f32_16x16x32_bf16(z8[k][1], b1k1, acca, 0, 0, 0);
            accb = __builtin_amdgcn_mfma_f32_16x16x32_bf16(z8[k][0], b2k0, accb, 0, 0, 0);
            accb = __builtin_amdgcn_mfma_f32_16x16x32_bf16(z8[k][1], b2k1, accb, 0, 0, 0);
            int col = n * 16 + m16;
#pragma unroll
            for (int r = 0; r < 4; ++r) {
                int row = j0 + h * 16 + quad * 4 + r;
                if (row < P) {
                    jb.zc[((size_t)gbase + row) * HID + col]  = __float2bfloat16(acca[r]);
                    jb.m1g[((size_t)gbase + row) * HID + col] = __float2bfloat16(accb[r]);
                }
            }
        }
    }
}

__global__ __launch_bounds__(1024, 1)
void fused23a_k(FJob j3, FJob j2, float* __restrict__ comb, int G) {
    __shared__ __align__(16) bf16 mLDS[MROWS * HID];   // 145920 B
    __shared__ __align__(16) bf16 wstage[8768];        //  17536 B
    int b = blockIdx.x;
    int g = b >> 1, h = b & 1;
    if (h == 0 && threadIdx.x < 128) comb[g * 192 + 64 + threadIdx.x] = 0.f;
    run_k1(j3, g, h, mLDS, wstage);
    __syncthreads();
    run_k1(j2, g, h, mLDS, wstage);
}

__device__ __forceinline__ void run_k2(const FJob& jb, int g, int h,
                                       bf16* mLDS, float* part, float* comb) {
    int t = threadIdx.x;
    const int P = jb.P;
    const int gbase = g * P;
    int lane = t & 63, wv = t >> 6, quad = lane >> 4, m16 = lane & 15;
    // stage m1 (full graph) global -> LDS, swizzled
    for (int i = t; i < P * 8; i += 1024) {
        int row = i >> 3, ch = i & 7;
        u4v v = *(const u4v*)(jb.m1g + ((size_t)gbase + row) * HID + ch * 8);
        *(u4v*)(mLDS + msw(row, ch)) = v;
    }
    __syncthreads();
    float ps[16];
#pragma unroll
    for (int j = 0; j < 16; ++j) ps[j] = 0.f;
#pragma unroll
    for (int k = 0; k < 3; ++k) {
        int tile = wv + k * 16;
        if (tile >= jb.ntiles) continue;
        int row = tile * 32 + h * 16 + m16;
        if (row < P) {
            float acc[16];
#pragma unroll
            for (int j = 0; j < 16; ++j) acc[j] = 0.f;
            size_t gr = (size_t)gbase + row;
            u4v zc0 = *(const u4v*)(jb.zc + gr * HID + quad * 8);
            u4v zc1 = *(const u4v*)(jb.zc + gr * HID + 32 + quad * 8);
            accu4(zc0, acc); accu4(zc1, acc + 8);
            int cnt = jb.cnt[gr];
            const u16* cs = jb.csrc + gr * (size_t)jb.pad;
            int kk = 0;
            for (; kk + 4 <= cnt; kk += 4) {
                int n0 = cs[kk], n1 = cs[kk + 1], n2 = cs[kk + 2], n3 = cs[kk + 3];
                naccum(mLDS, n0, quad, acc); naccum(mLDS, n1, quad, acc);
                naccum(mLDS, n2, quad, acc); naccum(mLDS, n3, quad, acc);
            }
            for (; kk < cnt; ++kk) naccum(mLDS, cs[kk], quad, acc);
#pragma unroll
            for (int j = 0; j < 16; ++j) ps[j] += fmaxf(acc[j], 0.f);
        }
    }
#pragma unroll
    for (int j = 0; j < 16; ++j) {
        ps[j] += __shfl_xor(ps[j], 1, 64);
        ps[j] += __shfl_xor(ps[j], 2, 64);
        ps[j] += __shfl_xor(ps[j], 4, 64);
        ps[j] += __shfl_xor(ps[j], 8, 64);
    }
    if (m16 == 0) {
#pragma unroll
        for (int kt = 0; kt < 2; ++kt)
#pragma unroll
            for (int e = 0; e < 8; ++e)
                part[wv * 64 + kt * 32 + quad * 8 + e] = ps[kt * 8 + e];
    }
    __syncthreads();
    if (t < 64) {
        float s = 0.f;
#pragma unroll
        for (int w = 0; w < 16; ++w) s += part[w * 64 + t];
        atomicAdd(&comb[g * 192 + jb.comboff + t], s);
    }
    __syncthreads();
}

__global__ __launch_bounds__(1024, 1)
void fused23b_k(FJob j3, FJob j2, float* __restrict__ comb, int G) {
    __shared__ __align__(16) bf16 mLDS[MROWS * HID];
    __shared__ float part[1024];
    int b = blockIdx.x;
    int g = b >> 1, h = b & 1;
    run_k2(j3, g, h, mLDS, part, comb);
    run_k2(j2, g, h, mLDS, part, comb);
}

// -------- classifier
__global__ void classifier_k(const float* __restrict__ comb,
                             const float* __restrict__ cW1, const float* __restrict__ cb1,
                             const float* __restrict__ cW2, const float* __restrict__ cb2,
                             float* __restrict__ out) {
    __shared__ float row[192];
    __shared__ float hid[64];
    int g = blockIdx.x, t = threadIdx.x;
    for (int i = t; i < 192; i += 64) row[i] = comb[g * 192 + i];
    __syncthreads();
    float acc = cb1[t];
#pragma unroll 8
    for (int k = 0; k < 192; ++k) acc += row[k] * cW1[t * 192 + k];
    hid[t] = fmaxf(acc, 0.f);
    __syncthreads();
    if (t < 10) {
        float o = cb2[t];
#pragma unroll
        for (int k = 0; k < 64; ++k) o += hid[k] * cW2[t * 64 + k];
        out[g * 10 + t] = o;
    }
}

static inline int cdiv(long long a, long long b) { return (int)((a + b - 1) / b); }

extern "C" void kernel_launch(void* const* d_in, const int* in_sizes, int n_in,
                              void* d_out, int out_size, void* d_ws, size_t ws_size,
                              hipStream_t stream) {
    const float* x        = (const float*)d_in[0];
    const int*   eidx     = (const int*)d_in[1];
    const int*   gu2      = (const int*)d_in[3];
    const int*   gv2      = (const int*)d_in[4];
    const float* iso2     = (const float*)d_in[5];
    const int*   tedges   = (const int*)d_in[6];
    const int*   ga3      = (const int*)d_in[8];
    const int*   gb3      = (const int*)d_in[9];
    const int*   gc3      = (const int*)d_in[10];
    const float* iso3     = (const float*)d_in[11];
    const int*   hedges   = (const int*)d_in[12];
    const float* g1W1[3]  = {(const float*)d_in[14], (const float*)d_in[16], (const float*)d_in[18]};
    const float* g1W2[3]  = {(const float*)d_in[15], (const float*)d_in[17], (const float*)d_in[19]};
    const float* g2W1_0   = (const float*)d_in[20];
    const float* g2W2_0   = (const float*)d_in[21];
    const float* g2W1_1   = (const float*)d_in[22];
    const float* g2W2_1   = (const float*)d_in[23];
    const float* g3W1_0   = (const float*)d_in[24];
    const float* g3W2_0   = (const float*)d_in[25];
    const float* g3W1_1   = (const float*)d_in[26];
    const float* g3W2_1   = (const float*)d_in[27];
    const float* cW1      = (const float*)d_in[28];
    const float* cb1      = (const float*)d_in[29];
    const float* cW2      = (const float*)d_in[30];
    const float* cb2      = (const float*)d_in[31];
    float* out = (float*)d_out;

    const int N  = in_sizes[0] / 32;       // 2560
    const int E1 = in_sizes[1] / 2;
    const int n2 = in_sizes[3];            // 24320
    const int E2 = in_sizes[6] / 2;
    const int n3 = in_sizes[8];            // 145920
    const int E3 = in_sizes[12] / 2;
    const int G  = out_size / 10;          // 128
    const int per1 = N / G, per2 = n2 / G, per3 = n3 / G;

    // ---- workspace carve-up (~67 MB total)
    float* ws = (float*)d_ws;
    size_t off = 0;
    auto alloc = [&](size_t n) { off = (off + 3) & ~(size_t)3; float* p = ws + off; off += n; return p; };
    const size_t NH = (size_t)N * HID;
    bf162* hUi = (bf162*)alloc(NH); bf162* hVi = (bf162*)alloc(NH);
    bf162* hAi = (bf162*)alloc(NH); bf162* hBi = (bf162*)alloc(NH); bf162* hCi = (bf162*)alloc(NH);
    bf16* z2c = (bf16*)alloc((size_t)n2 * HID / 2 + 64);
    bf16* z3c = (bf16*)alloc((size_t)n3 * HID / 2 + 64);
    bf16* m2g = (bf16*)alloc((size_t)n2 * HID / 2 + 64);
    bf16* m3g = (bf16*)alloc((size_t)n3 * HID / 2 + 64);
    float* comb = alloc((size_t)G * 192);
    int* iws = (int*)(ws + off);
    size_t ioff = 0;
    auto ialloc = [&](size_t n) { int* p = iws + ioff; ioff += n; return p; };
    int* cur1 = ialloc(N); int* cur2 = ialloc(n2); int* cur3 = ialloc(n3);   // contiguous
    u16* u16ws = (u16*)(iws + ioff);
    size_t uoff = 0;
    auto ualloc = [&](size_t n) { u16* p = u16ws + uoff; uoff += n; return p; };
    u16* csrc1 = ualloc((size_t)N * PAD1);
    u16* csrc2 = ualloc((size_t)n2 * PAD2);
    u16* csrc3 = ualloc((size_t)n3 * PAD3);
    (void)ws_size;

    dim3 B256(256);

    // ---- padded CSR build: zero + fill (2 dispatches)
    int ncnt = N + n2 + n3;
    zero_k<<<cdiv(ncnt, 256), B256, 0, stream>>>(cur1, ncnt);
    int ne1 = cdiv(E1, 256), ne2 = cdiv(E2, 256), ne3 = cdiv(E3, 256);
    fillp_k<<<ne1 + ne2 + ne3, B256, 0, stream>>>(
        eidx, E1, cur1, csrc1, PAD1, per1,
        tedges, E2, cur2, csrc2, PAD2, per2,
        hedges, E3, cur3, csrc3, PAD3, per3, ne1, ne2);

    // ---- level 1 GNN + segsum + 5 table projections (1 dispatch, 1024 thr)
    {
        TJobs5 jobs;
        jobs.j[0] = {g2W1_0, g2W2_0, hUi, 129, 0};
        jobs.j[1] = {g2W1_0, g2W2_0, hVi, 129, 64};
        jobs.j[2] = {g3W1_0, g3W2_0, hAi, 196, 0};
        jobs.j[3] = {g3W1_0, g3W2_0, hBi, 196, 64};
        jobs.j[4] = {g3W1_0, g3W2_0, hCi, 196, 128};
        level1T_k<<<G, 1024, 0, stream>>>(x, cur1, csrc1,
            g1W1[0], g1W2[0], g1W1[1], g1W2[1], g1W1[2], g1W2[2], jobs, comb, per1);
    }

    // ---- levels 2+3: split K1/K2, (graph, half) blocks
    {
        FJob j3, j2;
        j3.tA = hAi; j3.tB = hBi; j3.tC = hCi;
        j3.ga = ga3; j3.gb = gb3; j3.gc = gc3;
        j3.iso = iso3; j3.wc1 = g3W1_0 + 192; j3.wc2 = g3W2_0 + 192; j3.ldw = 196; j3.isoC = 4;
        j3.Wl1 = g3W1_1; j3.Wl2 = g3W2_1;
        j3.csrc = csrc3; j3.cnt = cur3; j3.pad = PAD3;
        j3.zc = z3c; j3.m1g = m3g;
        j3.P = per3; j3.ntiles = (per3 + 31) >> 5; j3.comboff = 128;

        j2.tA = hUi; j2.tB = hVi; j2.tC = nullptr;
        j2.ga = gu2; j2.gb = gv2; j2.gc = nullptr;
        j2.iso = iso2; j2.wc1 = g2W1_0 + 128; j2.wc2 = g2W2_0 + 128; j2.ldw = 129; j2.isoC = 1;
        j2.Wl1 = g2W1_1; j2.Wl2 = g2W2_1;
        j2.csrc = csrc2; j2.cnt = cur2; j2.pad = PAD2;
        j2.zc = z2c; j2.m1g = m2g;
        j2.P = per2; j2.ntiles = (per2 + 31) >> 5; j2.comboff = 64;

        fused23a_k<<<2 * G, 1024, 0, stream>>>(j3, j2, comb, G);
        fused23b_k<<<2 * G, 1024, 0, stream>>>(j3, j2, comb, G);
    }

    // ---- classifier
    classifier_k<<<G, 64, 0, stream>>>(comb, cW1, cb1, cW2, cb2, out);
}

// Round 6
// 334.462 us; speedup vs baseline: 1.3543x; 1.3543x over previous
//
#include <hip/hip_runtime.h>
#include <hip/hip_bf16.h>

#define HID 64
#define MROWS 1140   // C(20,3) rows per graph at level 3
#define PAD1 20      // level-1 in-degree <= 19
#define PAD2 40      // level-2 in-degree <= 38
#define PAD3 60      // level-3 in-degree <= 54

typedef __hip_bfloat16  bf16;
typedef __hip_bfloat162 bf162;
typedef unsigned short  u16;
typedef __attribute__((ext_vector_type(8))) short bf8v;
typedef __attribute__((ext_vector_type(4))) float f4v;
typedef __attribute__((ext_vector_type(4))) unsigned int u4v;
__device__ __forceinline__ float bl(bf16 h) { return __bfloat162float(h); }

// ======== padded CSR build: zero + fill ========
__global__ void zero_k(int* p, int n) {
    int i = blockIdx.x * 256 + threadIdx.x;
    if (i < n) p[i] = 0;
}

__global__ void fillp_k(const int* e1, int E1, int* c1, u16* s1, int p1, int P1_,
                        const int* e2, int E2, int* c2, u16* s2, int p2, int P2_,
                        const int* e3, int E3, int* c3, u16* s3, int p3, int P3_,
                        int nb1, int nb2) {
    int b = blockIdx.x;
    const int* edges; int E; int* cur; u16* csrc; int pad; int P; int lb;
    if (b < nb1)            { edges = e1; E = E1; cur = c1; csrc = s1; pad = p1; P = P1_; lb = b; }
    else if (b < nb1 + nb2) { edges = e2; E = E2; cur = c2; csrc = s2; pad = p2; P = P2_; lb = b - nb1; }
    else                    { edges = e3; E = E3; cur = c3; csrc = s3; pad = p3; P = P3_; lb = b - nb1 - nb2; }
    int e = lb * 256 + threadIdx.x;
    if (e >= E) return;
    int d = edges[E + e];
    int slot = atomicAdd(&cur[d], 1);
    if (slot < pad) csrc[(size_t)d * pad + slot] = (u16)(edges[e] % P);   // local id
}

// ======== level-1 GNN (round-4 proven structure) + h write + segsum ========
__global__ __launch_bounds__(256)
void level1_k(const float* __restrict__ x,
              const int* __restrict__ cnt1, const u16* __restrict__ csrc1,
              const float* __restrict__ W10, const float* __restrict__ W20,
              const float* __restrict__ W11, const float* __restrict__ W21,
              const float* __restrict__ W12, const float* __restrict__ W22,
              float* __restrict__ hout, float* __restrict__ comb, int nper) {
    __shared__ float hbuf[20][64];
    __shared__ float mbuf[20][64];
    __shared__ float wl1[64 * 64];
    __shared__ float wl2[64 * 64];
    int g = blockIdx.x, t = threadIdx.x;
    int wv = t >> 6, lane = t & 63;
    int base = g * nper;
    for (int i = t; i < 20 * 32; i += 256)
        hbuf[i >> 5][i & 31] = x[(size_t)base * 32 + i];
    const float* W1s[3] = {W10, W11, W12};
    const float* W2s[3] = {W20, W21, W22};
#pragma unroll 1
    for (int l = 0; l < 3; ++l) {
        int K = (l == 0) ? 32 : 64;
        const float* W1 = W1s[l];
        const float* W2 = W2s[l];
        __syncthreads();
        for (int i = t; i < K * 64; i += 256) {
            int k = i >> 6, col = i & 63;
            wl1[i] = W1[col * K + k];
            wl2[i] = W2[col * K + k];
        }
        __syncthreads();
        float accz[5], accm[5];
#pragma unroll
        for (int ri = 0; ri < 5; ++ri) {
            int r = wv + ri * 4;
            float az = 0.f, am = 0.f;
            for (int k = 0; k < K; ++k) {
                float hv = hbuf[r][k];
                az = fmaf(hv, wl1[k * 64 + lane], az);
                am = fmaf(hv, wl2[k * 64 + lane], am);
            }
            accz[ri] = az; accm[ri] = am;
        }
        __syncthreads();
#pragma unroll
        for (int ri = 0; ri < 5; ++ri)
            mbuf[wv + ri * 4][lane] = accm[ri];
        __syncthreads();
#pragma unroll
        for (int ri = 0; ri < 5; ++ri) {
            int r = wv + ri * 4;
            float acc = accz[ri];
            int cnt = cnt1[base + r];
            const u16* cs = csrc1 + (size_t)(base + r) * PAD1;
            for (int k = 0; k < cnt; ++k)
                acc += mbuf[cs[k]][lane];
            hbuf[r][lane] = fmaxf(acc, 0.f);
        }
    }
    __syncthreads();
    for (int i = t; i < 20 * 64; i += 256)
        hout[(size_t)base * 64 + i] = hbuf[i >> 6][i & 63];
    if (t < 64) {
        float s = 0.f;
#pragma unroll
        for (int r = 0; r < 20; ++r) s += hbuf[r][t];
        comb[g * 192 + t] = s;   // level-1 embedding, cols 0..63
    }
}

// ======== FUSED levels 2+3, split across (graph, half); hs computed in-block ====
struct FJob {
    const float *hsrc;              // level-1 h, fp32 [N][64]
    const float *W1t, *W2t;         // level-0 weights (full mats, row stride ldw)
    const int *ga, *gb, *gc;        // global node ids per row (gc null => level 2)
    const float *iso;               // level3: float4 one-hot; level2: float
    const float *wc1, *wc2; int ldw, isoC, nT;
    const float *Wl1, *Wl2;         // layer-1 weights [64][64]
    const u16 *csrc; const int *cnt; int pad;   // padded CSR (local ids)
    bf16 *zc; bf16 *m1g;            // layer-1 preact + message scratch (bf16 [n][64])
    int P, ntiles, comboff;
};

__device__ __forceinline__ int msw(int row, int ch) {
    return (row << 6) + ((ch ^ (row & 7)) << 3);
}
__device__ __forceinline__ void accu4(u4v v, float* f) {
#pragma unroll
    for (int i = 0; i < 4; ++i) {
        f[2 * i]     += __uint_as_float(v[i] << 16);
        f[2 * i + 1] += __uint_as_float(v[i] & 0xffff0000u);
    }
}
__device__ __forceinline__ void accxy4(u4v v, float* zx, float* zy) {
#pragma unroll
    for (int i = 0; i < 4; ++i) {
        zx[i] += __uint_as_float(v[i] << 16);
        zy[i] += __uint_as_float(v[i] & 0xffff0000u);
    }
}
__device__ __forceinline__ bf8v pack8(const float* f) {
    bf16 tmp[8];
#pragma unroll
    for (int e = 0; e < 8; ++e) tmp[e] = __float2bfloat16(f[e]);
    bf8v r; __builtin_memcpy(&r, tmp, 16); return r;
}
__device__ __forceinline__ bf8v pack8relu(const float* f) {
    bf16 tmp[8];
#pragma unroll
    for (int e = 0; e < 8; ++e) tmp[e] = __float2bfloat16(fmaxf(f[e], 0.f));
    bf8v r; __builtin_memcpy(&r, tmp, 16); return r;
}
__device__ __forceinline__ u4v asu4(bf8v v) { u4v r; __builtin_memcpy(&r, &v, 16); return r; }
__device__ __forceinline__ void hsacc(const bf162* tb, int nd, int c4, float* zx, float* zy) {
    u4v v0 = *(const u4v*)(tb + (nd << 6) + (((c4    ) ^ (nd & 15)) << 2));
    u4v v1 = *(const u4v*)(tb + (nd << 6) + (((c4 + 1) ^ (nd & 15)) << 2));
    accxy4(v0, zx, zy);
    accxy4(v1, zx + 4, zy + 4);
}
__device__ __forceinline__ void hsaccY(const bf162* tb, int nd, int c4, float* zy) {
    u4v v0 = *(const u4v*)(tb + (nd << 6) + (((c4    ) ^ (nd & 15)) << 2));
    u4v v1 = *(const u4v*)(tb + (nd << 6) + (((c4 + 1) ^ (nd & 15)) << 2));
#pragma unroll
    for (int i = 0; i < 4; ++i) {
        zy[i]     += __uint_as_float(v0[i] & 0xffff0000u);
        zy[4 + i] += __uint_as_float(v1[i] & 0xffff0000u);
    }
}
__device__ __forceinline__ void naccum(const bf16* mL, int nbr, int quad, float* acc) {
    u4v v0 = *(const u4v*)(mL + msw(nbr, quad));
    u4v v1 = *(const u4v*)(mL + msw(nbr, quad + 4));
    accu4(v0, acc); accu4(v1, acc + 8);
}

__device__ __forceinline__ void run_k1(const FJob& jb, int g, int h,
                                       bf16* mLDS, bf16* wstage) {
    int t = threadIdx.x;
    const int P = jb.P, nT = jb.nT;
    const int gbase = g * P, nb20 = g * 20;
    int lane = t & 63, wv = t >> 6, quad = lane >> 4, m16 = lane & 15;

    // ---- P0: COMPUTE projected node tables from h (swizzled), + iso-weight table.
    // wave = one (table,node): 64 lanes = 64 out-features; h row broadcast (L1),
    // W rows (one per lane) become L1-resident across the k loop.
    bf162* hsA = (bf162*)wstage;
    const bf162* hsB = hsA + 1280;
    const bf162* hsC = hsA + 2560;
    for (int i = t; i < nT * 1280; i += 1024) {
        int table = i / 1280, rem = i - table * 1280;
        int node = rem >> 6, f = rem & 63;
        const float* hr = jb.hsrc + (size_t)(nb20 + node) * 64;
        const float* w1 = jb.W1t + (size_t)f * jb.ldw + table * 64;
        const float* w2 = jb.W2t + (size_t)f * jb.ldw + table * 64;
        float sx = 0.f, sy = 0.f;
        for (int k = 0; k < 64; ++k) {
            float hv = hr[k];
            sx = fmaf(hv, w1[k], sx);
            sy = fmaf(hv, w2[k], sy);
        }
        int c4 = f >> 2;
        bf162 v; v.x = __float2bfloat16(sx); v.y = __float2bfloat16(sy);
        hsA[table * 1280 + (node << 6) + ((c4 ^ (node & 15)) << 2) + (f & 3)] = v;
    }
    float* wcT = (float*)(wstage + 7680);   // [2 mats][4 c][64 f]
    if (t < 512) {
        int mat = t >> 8, c = (t >> 6) & 3, f = t & 63;
        const float* W = mat ? jb.wc2 : jb.wc1;
        wcT[mat * 256 + c * 64 + f] = (c < jb.isoC) ? W[f * jb.ldw + c] : 0.f;
    }
    __syncthreads();

    // ---- P1: layer-0 gather -> z (regs, owned rt only) + m0 (LDS, all rows)
    bf8v z8[3][2];
#pragma unroll
    for (int k = 0; k < 3; ++k) {
        int tile = wv + k * 16;
        if (tile >= jb.ntiles) continue;
#pragma unroll
        for (int rt = 0; rt < 2; ++rt) {
            bool own = (rt == h);
            int row = tile * 32 + rt * 16 + m16;
            float zx[16], zy[16];
#pragma unroll
            for (int j = 0; j < 16; ++j) { zx[j] = 0.f; zy[j] = 0.f; }
            if (row < P) {
                size_t gr = (size_t)gbase + row;
                int na = jb.ga[gr] - nb20;
                int nb = jb.gb[gr] - nb20;
                int nc = 0;
                const float* w1r; const float* w2r; float isw;
                if (nT == 3) {
                    nc = jb.gc[gr] - nb20;
                    float4 iv = ((const float4*)jb.iso)[gr];   // one-hot eye(4)[ec]
                    int ec = (int)(iv.y + 2.f * iv.z + 3.f * iv.w + 0.5f);
                    w1r = wcT + ec * 64; w2r = wcT + 256 + ec * 64; isw = 1.f;
                } else {
                    w1r = wcT; w2r = wcT + 256; isw = jb.iso[gr];
                }
#pragma unroll
                for (int kt = 0; kt < 2; ++kt) {
                    int c4 = kt * 8 + quad * 2;
                    int f0 = kt * 32 + quad * 8;
                    if (own) {
                        hsacc(hsA, na, c4, zx + kt * 8, zy + kt * 8);
                        hsacc(hsB, nb, c4, zx + kt * 8, zy + kt * 8);
                        if (nT == 3) hsacc(hsC, nc, c4, zx + kt * 8, zy + kt * 8);
#pragma unroll
                        for (int e = 0; e < 8; ++e)
                            zx[kt * 8 + e] = fmaf(isw, w1r[f0 + e], zx[kt * 8 + e]);
                    } else {
                        hsaccY(hsA, na, c4, zy + kt * 8);
                        hsaccY(hsB, nb, c4, zy + kt * 8);
                        if (nT == 3) hsaccY(hsC, nc, c4, zy + kt * 8);
                    }
#pragma unroll
                    for (int e = 0; e < 8; ++e)
                        zy[kt * 8 + e] = fmaf(isw, w2r[f0 + e], zy[kt * 8 + e]);
                }
                *(bf8v*)(mLDS + msw(row, quad))     = pack8(zy);
                *(bf8v*)(mLDS + msw(row, quad + 4)) = pack8(zy + 8);
            }
            if (own) { z8[k][0] = pack8(zx); z8[k][1] = pack8(zx + 8); }
        }
    }
    __syncthreads();

    // ---- P2: stage layer-1 W frags (frag-major) + neighsum-1 for owned rows
    for (int i = t; i < 8192; i += 1024) {
        int e = i & 7, mm = (i >> 3) & 15, qq = (i >> 7) & 3;
        int kk = (i >> 9) & 1, mat = (i >> 10) & 1, nn = i >> 11;
        const float* W = mat ? jb.Wl2 : jb.Wl1;
        wstage[i] = __float2bfloat16(W[(nn * 16 + mm) * HID + kk * 32 + qq * 8 + e]);
    }
#pragma unroll
    for (int k = 0; k < 3; ++k) {
        int tile = wv + k * 16;
        if (tile >= jb.ntiles) continue;
        int row = tile * 32 + h * 16 + m16;
        float acc[16];
#pragma unroll
        for (int j = 0; j < 16; ++j) acc[j] = 0.f;
        accu4(asu4(z8[k][0]), acc);
        accu4(asu4(z8[k][1]), acc + 8);
        if (row < P) {
            size_t gr = (size_t)gbase + row;
            int cnt = jb.cnt[gr];
            const u16* cs = jb.csrc + gr * (size_t)jb.pad;
            int kk = 0;
            for (; kk + 4 <= cnt; kk += 4) {
                int n0 = cs[kk], n1 = cs[kk + 1], n2 = cs[kk + 2], n3 = cs[kk + 3];
                naccum(mLDS, n0, quad, acc); naccum(mLDS, n1, quad, acc);
                naccum(mLDS, n2, quad, acc); naccum(mLDS, n3, quad, acc);
            }
            for (; kk < cnt; ++kk) naccum(mLDS, cs[kk], quad, acc);
        }
        z8[k][0] = pack8relu(acc);
        z8[k][1] = pack8relu(acc + 8);
    }
    __syncthreads();

    // ---- P3: dual MFMA GEMM (owned rt only). zc + m1 -> GLOBAL.
#pragma unroll
    for (int k = 0; k < 3; ++k) {
        int tile = wv + k * 16;
        if (tile >= jb.ntiles) continue;
        int j0 = tile * 32;
#pragma unroll
        for (int n = 0; n < 4; ++n) {
            const bf8v b1k0 = *(const bf8v*)(wstage + ((((n*2+0)*2+0)*4+quad)*16+m16)*8);
            const bf8v b1k1 = *(const bf8v*)(wstage + ((((n*2+0)*2+1)*4+quad)*16+m16)*8);
            const bf8v b2k0 = *(const bf8v*)(wstage + ((((n*2+1)*2+0)*4+quad)*16+m16)*8);
            const bf8v b2k1 = *(const bf8v*)(wstage + ((((n*2+1)*2+1)*4+quad)*16+m16)*8);
            f4v acca = {0.f, 0.f, 0.f, 0.f};
            f4v accb = {0.f, 0.f, 0.f, 0.f};
            acca = __builtin_amdgcn_mfma_f32_16x16x32_bf16(z8[k][0], b1k0, acca, 0, 0, 0);
            acca = __builtin_amdgcn_mfma_f32_16x16x32_bf16(z8[k][1], b1k1, acca, 0, 0, 0);
            accb = __builtin_amdgcn_mfma_f32_16x16x32_bf16(z8[k][0], b2k0, accb, 0, 0, 0);
            accb = __builtin_amdgcn_mfma_f32_16x16x32_bf16(z8[k][1], b2k1, accb, 0, 0, 0);
            int col = n * 16 + m16;
#pragma unroll
            for (int r = 0; r < 4; ++r) {
                int row = j0 + h * 16 + quad * 4 + r;
                if (row < P) {
                    jb.zc[((size_t)gbase + row) * HID + col]  = __float2bfloat16(acca[r]);
                    jb.m1g[((size_t)gbase + row) * HID + col] = __float2bfloat16(accb[r]);
                }
            }
        }
    }
}

__global__ __launch_bounds__(1024, 1)
void fused23a_k(FJob j3, FJob j2, float* __restrict__ comb, int G) {
    __shared__ __align__(16) bf16 mLDS[MROWS * HID];   // 145920 B
    __shared__ __align__(16) bf16 wstage[8768];        //  17536 B
    int b = blockIdx.x;
    int g = b >> 1, h = b & 1;
    if (h == 0 && threadIdx.x < 128) comb[g * 192 + 64 + threadIdx.x] = 0.f;
    run_k1(j3, g, h, mLDS, wstage);
    __syncthreads();
    run_k1(j2, g, h, mLDS, wstage);
}

__device__ __forceinline__ void run_k2(const FJob& jb, int g, int h,
                                       bf16* mLDS, float* part, float* comb) {
    int t = threadIdx.x;
    const int P = jb.P;
    const int gbase = g * P;
    int lane = t & 63, wv = t >> 6, quad = lane >> 4, m16 = lane & 15;
    // stage m1 (full graph) global -> LDS, swizzled
    for (int i = t; i < P * 8; i += 1024) {
        int row = i >> 3, ch = i & 7;
        u4v v = *(const u4v*)(jb.m1g + ((size_t)gbase + row) * HID + ch * 8);
        *(u4v*)(mLDS + msw(row, ch)) = v;
    }
    __syncthreads();
    float ps[16];
#pragma unroll
    for (int j = 0; j < 16; ++j) ps[j] = 0.f;
#pragma unroll
    for (int k = 0; k < 3; ++k) {
        int tile = wv + k * 16;
        if (tile >= jb.ntiles) continue;
        int row = tile * 32 + h * 16 + m16;
        if (row < P) {
            float acc[16];
#pragma unroll
            for (int j = 0; j < 16; ++j) acc[j] = 0.f;
            size_t gr = (size_t)gbase + row;
            u4v zc0 = *(const u4v*)(jb.zc + gr * HID + quad * 8);
            u4v zc1 = *(const u4v*)(jb.zc + gr * HID + 32 + quad * 8);
            accu4(zc0, acc); accu4(zc1, acc + 8);
            int cnt = jb.cnt[gr];
            const u16* cs = jb.csrc + gr * (size_t)jb.pad;
            int kk = 0;
            for (; kk + 4 <= cnt; kk += 4) {
                int n0 = cs[kk], n1 = cs[kk + 1], n2 = cs[kk + 2], n3 = cs[kk + 3];
                naccum(mLDS, n0, quad, acc); naccum(mLDS, n1, quad, acc);
                naccum(mLDS, n2, quad, acc); naccum(mLDS, n3, quad, acc);
            }
            for (; kk < cnt; ++kk) naccum(mLDS, cs[kk], quad, acc);
#pragma unroll
            for (int j = 0; j < 16; ++j) ps[j] += fmaxf(acc[j], 0.f);
        }
    }
#pragma unroll
    for (int j = 0; j < 16; ++j) {
        ps[j] += __shfl_xor(ps[j], 1, 64);
        ps[j] += __shfl_xor(ps[j], 2, 64);
        ps[j] += __shfl_xor(ps[j], 4, 64);
        ps[j] += __shfl_xor(ps[j], 8, 64);
    }
    if (m16 == 0) {
#pragma unroll
        for (int kt = 0; kt < 2; ++kt)
#pragma unroll
            for (int e = 0; e < 8; ++e)
                part[wv * 64 + kt * 32 + quad * 8 + e] = ps[kt * 8 + e];
    }
    __syncthreads();
    if (t < 64) {
        float s = 0.f;
#pragma unroll
        for (int w = 0; w < 16; ++w) s += part[w * 64 + t];
        atomicAdd(&comb[g * 192 + jb.comboff + t], s);
    }
    __syncthreads();
}

__global__ __launch_bounds__(1024, 1)
void fused23b_k(FJob j3, FJob j2, float* __restrict__ comb, int G) {
    __shared__ __align__(16) bf16 mLDS[MROWS * HID];
    __shared__ float part[1024];
    int b = blockIdx.x;
    int g = b >> 1, h = b & 1;
    run_k2(j3, g, h, mLDS, part, comb);
    run_k2(j2, g, h, mLDS, part, comb);
}

// -------- classifier
__global__ void classifier_k(const float* __restrict__ comb,
                             const float* __restrict__ cW1, const float* __restrict__ cb1,
                             const float* __restrict__ cW2, const float* __restrict__ cb2,
                             float* __restrict__ out) {
    __shared__ float row[192];
    __shared__ float hid[64];
    int g = blockIdx.x, t = threadIdx.x;
    for (int i = t; i < 192; i += 64) row[i] = comb[g * 192 + i];
    __syncthreads();
    float acc = cb1[t];
#pragma unroll 8
    for (int k = 0; k < 192; ++k) acc += row[k] * cW1[t * 192 + k];
    hid[t] = fmaxf(acc, 0.f);
    __syncthreads();
    if (t < 10) {
        float o = cb2[t];
#pragma unroll
        for (int k = 0; k < 64; ++k) o += hid[k] * cW2[t * 64 + k];
        out[g * 10 + t] = o;
    }
}

static inline int cdiv(long long a, long long b) { return (int)((a + b - 1) / b); }

extern "C" void kernel_launch(void* const* d_in, const int* in_sizes, int n_in,
                              void* d_out, int out_size, void* d_ws, size_t ws_size,
                              hipStream_t stream) {
    const float* x        = (const float*)d_in[0];
    const int*   eidx     = (const int*)d_in[1];
    const int*   gu2      = (const int*)d_in[3];
    const int*   gv2      = (const int*)d_in[4];
    const float* iso2     = (const float*)d_in[5];
    const int*   tedges   = (const int*)d_in[6];
    const int*   ga3      = (const int*)d_in[8];
    const int*   gb3      = (const int*)d_in[9];
    const int*   gc3      = (const int*)d_in[10];
    const float* iso3     = (const float*)d_in[11];
    const int*   hedges   = (const int*)d_in[12];
    const float* g1W1[3]  = {(const float*)d_in[14], (const float*)d_in[16], (const float*)d_in[18]};
    const float* g1W2[3]  = {(const float*)d_in[15], (const float*)d_in[17], (const float*)d_in[19]};
    const float* g2W1_0   = (const float*)d_in[20];
    const float* g2W2_0   = (const float*)d_in[21];
    const float* g2W1_1   = (const float*)d_in[22];
    const float* g2W2_1   = (const float*)d_in[23];
    const float* g3W1_0   = (const float*)d_in[24];
    const float* g3W2_0   = (const float*)d_in[25];
    const float* g3W1_1   = (const float*)d_in[26];
    const float* g3W2_1   = (const float*)d_in[27];
    const float* cW1      = (const float*)d_in[28];
    const float* cb1      = (const float*)d_in[29];
    const float* cW2      = (const float*)d_in[30];
    const float* cb2      = (const float*)d_in[31];
    float* out = (float*)d_out;

    const int N  = in_sizes[0] / 32;       // 2560
    const int E1 = in_sizes[1] / 2;
    const int n2 = in_sizes[3];            // 24320
    const int E2 = in_sizes[6] / 2;
    const int n3 = in_sizes[8];            // 145920
    const int E3 = in_sizes[12] / 2;
    const int G  = out_size / 10;          // 128
    const int per1 = N / G, per2 = n2 / G, per3 = n3 / G;

    // ---- workspace carve-up (~65 MB; round-4's passing layout was larger)
    float* ws = (float*)d_ws;
    size_t off = 0;
    auto alloc = [&](size_t n) { off = (off + 3) & ~(size_t)3; float* p = ws + off; off += n; return p; };
    const size_t NH = (size_t)N * HID;
    float* h0 = alloc(NH);
    bf16* z2c = (bf16*)alloc((size_t)n2 * HID / 2 + 64);
    bf16* z3c = (bf16*)alloc((size_t)n3 * HID / 2 + 64);
    bf16* m2g = (bf16*)alloc((size_t)n2 * HID / 2 + 64);
    bf16* m3g = (bf16*)alloc((size_t)n3 * HID / 2 + 64);
    float* comb = alloc((size_t)G * 192);
    int* iws = (int*)(ws + off);
    size_t ioff = 0;
    auto ialloc = [&](size_t n) { int* p = iws + ioff; ioff += n; return p; };
    int* cur1 = ialloc(N); int* cur2 = ialloc(n2); int* cur3 = ialloc(n3);   // contiguous
    u16* u16ws = (u16*)(iws + ioff);
    size_t uoff = 0;
    auto ualloc = [&](size_t n) { u16* p = u16ws + uoff; uoff += n; return p; };
    u16* csrc1 = ualloc((size_t)N * PAD1);
    u16* csrc2 = ualloc((size_t)n2 * PAD2);
    u16* csrc3 = ualloc((size_t)n3 * PAD3);
    (void)ws_size;

    dim3 B256(256);

    // ---- padded CSR build: zero + fill (2 dispatches)
    int ncnt = N + n2 + n3;
    zero_k<<<cdiv(ncnt, 256), B256, 0, stream>>>(cur1, ncnt);
    int ne1 = cdiv(E1, 256), ne2 = cdiv(E2, 256), ne3 = cdiv(E3, 256);
    fillp_k<<<ne1 + ne2 + ne3, B256, 0, stream>>>(
        eidx, E1, cur1, csrc1, PAD1, per1,
        tedges, E2, cur2, csrc2, PAD2, per2,
        hedges, E3, cur3, csrc3, PAD3, per3, ne1, ne2);

    // ---- level 1 GNN + h write + segsum (round-4 proven structure)
    level1_k<<<G, B256, 0, stream>>>(x, cur1, csrc1,
        g1W1[0], g1W2[0], g1W1[1], g1W2[1], g1W1[2], g1W2[2], h0, comb, per1);

    // ---- levels 2+3: split K1/K2, (graph, half) blocks; hs computed in-block
    {
        FJob j3, j2;
        j3.hsrc = h0; j3.W1t = g3W1_0; j3.W2t = g3W2_0;
        j3.ga = ga3; j3.gb = gb3; j3.gc = gc3;
        j3.iso = iso3; j3.wc1 = g3W1_0 + 192; j3.wc2 = g3W2_0 + 192;
        j3.ldw = 196; j3.isoC = 4; j3.nT = 3;
        j3.Wl1 = g3W1_1; j3.Wl2 = g3W2_1;
        j3.csrc = csrc3; j3.cnt = cur3; j3.pad = PAD3;
        j3.zc = z3c; j3.m1g = m3g;
        j3.P = per3; j3.ntiles = (per3 + 31) >> 5; j3.comboff = 128;

        j2.hsrc = h0; j2.W1t = g2W1_0; j2.W2t = g2W2_0;
        j2.ga = gu2; j2.gb = gv2; j2.gc = nullptr;
        j2.iso = iso2; j2.wc1 = g2W1_0 + 128; j2.wc2 = g2W2_0 + 128;
        j2.ldw = 129; j2.isoC = 1; j2.nT = 2;
        j2.Wl1 = g2W1_1; j2.Wl2 = g2W2_1;
        j2.csrc = csrc2; j2.cnt = cur2; j2.pad = PAD2;
        j2.zc = z2c; j2.m1g = m2g;
        j2.P = per2; j2.ntiles = (per2 + 31) >> 5; j2.comboff = 64;

        fused23a_k<<<2 * G, 1024, 0, stream>>>(j3, j2, comb, G);
        fused23b_k<<<2 * G, 1024, 0, stream>>>(j3, j2, comb, G);
    }

    // ---- classifier
    classifier_k<<<G, 64, 0, stream>>>(comb, cW1, cb1, cW2, cb2, out);
}

// Round 7
// 269.259 us; speedup vs baseline: 1.6823x; 1.2422x over previous
//
#include <hip/hip_runtime.h>
#include <hip/hip_bf16.h>

#define HID 64
#define MROWS 1140   // C(20,3) rows per graph at level 3
#define PAD1 20      // level-1 in-degree <= 19
#define PAD2 40      // level-2 in-degree <= 38
#define PAD3 60      // level-3 in-degree <= 54

typedef __hip_bfloat16  bf16;
typedef __hip_bfloat162 bf162;
typedef unsigned short  u16;
typedef __attribute__((ext_vector_type(8))) short bf8v;
typedef __attribute__((ext_vector_type(4))) float f4v;
typedef __attribute__((ext_vector_type(4))) unsigned int u4v;
__device__ __forceinline__ float bl(bf16 h) { return __bfloat162float(h); }

// ======== padded CSR build: zero + fill ========
__global__ void zero_k(int* p, int n) {
    int i = blockIdx.x * 256 + threadIdx.x;
    if (i < n) p[i] = 0;
}

__global__ void fillp_k(const int* e1, int E1, int* c1, u16* s1, int p1, int P1_,
                        const int* e2, int E2, int* c2, u16* s2, int p2, int P2_,
                        const int* e3, int E3, int* c3, u16* s3, int p3, int P3_,
                        int nb1, int nb2) {
    int b = blockIdx.x;
    const int* edges; int E; int* cur; u16* csrc; int pad; int P; int lb;
    if (b < nb1)            { edges = e1; E = E1; cur = c1; csrc = s1; pad = p1; P = P1_; lb = b; }
    else if (b < nb1 + nb2) { edges = e2; E = E2; cur = c2; csrc = s2; pad = p2; P = P2_; lb = b - nb1; }
    else                    { edges = e3; E = E3; cur = c3; csrc = s3; pad = p3; P = P3_; lb = b - nb1 - nb2; }
    int e = lb * 256 + threadIdx.x;
    if (e >= E) return;
    int d = edges[E + e];
    int slot = atomicAdd(&cur[d], 1);
    if (slot < pad) csrc[(size_t)d * pad + slot] = (u16)(edges[e] % P);   // local id
}

// ======== level-1 GNN (round-4 proven structure) + h write + segsum ========
__global__ __launch_bounds__(256)
void level1_k(const float* __restrict__ x,
              const int* __restrict__ cnt1, const u16* __restrict__ csrc1,
              const float* __restrict__ W10, const float* __restrict__ W20,
              const float* __restrict__ W11, const float* __restrict__ W21,
              const float* __restrict__ W12, const float* __restrict__ W22,
              float* __restrict__ hout, float* __restrict__ comb, int nper) {
    __shared__ float hbuf[20][64];
    __shared__ float mbuf[20][64];
    __shared__ float wl1[64 * 64];
    __shared__ float wl2[64 * 64];
    int g = blockIdx.x, t = threadIdx.x;
    int wv = t >> 6, lane = t & 63;
    int base = g * nper;
    for (int i = t; i < 20 * 32; i += 256)
        hbuf[i >> 5][i & 31] = x[(size_t)base * 32 + i];
    const float* W1s[3] = {W10, W11, W12};
    const float* W2s[3] = {W20, W21, W22};
#pragma unroll 1
    for (int l = 0; l < 3; ++l) {
        int K = (l == 0) ? 32 : 64;
        const float* W1 = W1s[l];
        const float* W2 = W2s[l];
        __syncthreads();
        for (int i = t; i < K * 64; i += 256) {
            int k = i >> 6, col = i & 63;
            wl1[i] = W1[col * K + k];
            wl2[i] = W2[col * K + k];
        }
        __syncthreads();
        float accz[5], accm[5];
#pragma unroll
        for (int ri = 0; ri < 5; ++ri) {
            int r = wv + ri * 4;
            float az = 0.f, am = 0.f;
            for (int k = 0; k < K; ++k) {
                float hv = hbuf[r][k];
                az = fmaf(hv, wl1[k * 64 + lane], az);
                am = fmaf(hv, wl2[k * 64 + lane], am);
            }
            accz[ri] = az; accm[ri] = am;
        }
        __syncthreads();
#pragma unroll
        for (int ri = 0; ri < 5; ++ri)
            mbuf[wv + ri * 4][lane] = accm[ri];
        __syncthreads();
#pragma unroll
        for (int ri = 0; ri < 5; ++ri) {
            int r = wv + ri * 4;
            float acc = accz[ri];
            int cnt = cnt1[base + r];
            const u16* cs = csrc1 + (size_t)(base + r) * PAD1;
            for (int k = 0; k < cnt; ++k)
                acc += mbuf[cs[k]][lane];
            hbuf[r][lane] = fmaxf(acc, 0.f);
        }
    }
    __syncthreads();
    for (int i = t; i < 20 * 64; i += 256)
        hout[(size_t)base * 64 + i] = hbuf[i >> 6][i & 63];
    if (t < 64) {
        float s = 0.f;
#pragma unroll
        for (int r = 0; r < 20; ++r) s += hbuf[r][t];
        comb[g * 192 + t] = s;   // level-1 embedding, cols 0..63
    }
}

// ======== FUSED levels 2+3, split across (graph, half); hs via MFMA in-block ====
struct FJob {
    const float *hsrc;              // level-1 h, fp32 [N][64]
    const float *W1t, *W2t;         // level-0 weights (full mats, row stride ldw)
    const int *ga, *gb, *gc;        // global node ids per row (gc null => level 2)
    const float *iso;               // level3: float4 one-hot; level2: float
    const float *wc1, *wc2; int ldw, isoC, nT;
    const float *Wl1, *Wl2;         // layer-1 weights [64][64]
    const u16 *csrc; const int *cnt; int pad;   // padded CSR (local ids)
    bf16 *zc; bf16 *m1g;            // layer-1 preact + message scratch (bf16 [n][64])
    int P, ntiles, comboff;
};

__device__ __forceinline__ int msw(int row, int ch) {
    return (row << 6) + ((ch ^ (row & 7)) << 3);
}
__device__ __forceinline__ void accu4(u4v v, float* f) {
#pragma unroll
    for (int i = 0; i < 4; ++i) {
        f[2 * i]     += __uint_as_float(v[i] << 16);
        f[2 * i + 1] += __uint_as_float(v[i] & 0xffff0000u);
    }
}
__device__ __forceinline__ void accxy4(u4v v, float* zx, float* zy) {
#pragma unroll
    for (int i = 0; i < 4; ++i) {
        zx[i] += __uint_as_float(v[i] << 16);
        zy[i] += __uint_as_float(v[i] & 0xffff0000u);
    }
}
__device__ __forceinline__ bf8v pack8(const float* f) {
    bf16 tmp[8];
#pragma unroll
    for (int e = 0; e < 8; ++e) tmp[e] = __float2bfloat16(f[e]);
    bf8v r; __builtin_memcpy(&r, tmp, 16); return r;
}
__device__ __forceinline__ bf8v pack8relu(const float* f) {
    bf16 tmp[8];
#pragma unroll
    for (int e = 0; e < 8; ++e) tmp[e] = __float2bfloat16(fmaxf(f[e], 0.f));
    bf8v r; __builtin_memcpy(&r, tmp, 16); return r;
}
__device__ __forceinline__ u4v asu4(bf8v v) { u4v r; __builtin_memcpy(&r, &v, 16); return r; }
__device__ __forceinline__ void hsacc(const bf162* tb, int nd, int c4, float* zx, float* zy) {
    u4v v0 = *(const u4v*)(tb + (nd << 6) + (((c4    ) ^ (nd & 15)) << 2));
    u4v v1 = *(const u4v*)(tb + (nd << 6) + (((c4 + 1) ^ (nd & 15)) << 2));
    accxy4(v0, zx, zy);
    accxy4(v1, zx + 4, zy + 4);
}
__device__ __forceinline__ void hsaccY(const bf162* tb, int nd, int c4, float* zy) {
    u4v v0 = *(const u4v*)(tb + (nd << 6) + (((c4    ) ^ (nd & 15)) << 2));
    u4v v1 = *(const u4v*)(tb + (nd << 6) + (((c4 + 1) ^ (nd & 15)) << 2));
#pragma unroll
    for (int i = 0; i < 4; ++i) {
        zy[i]     += __uint_as_float(v0[i] & 0xffff0000u);
        zy[4 + i] += __uint_as_float(v1[i] & 0xffff0000u);
    }
}
__device__ __forceinline__ void naccum(const bf16* mL, int nbr, int quad, float* acc) {
    u4v v0 = *(const u4v*)(mL + msw(nbr, quad));
    u4v v1 = *(const u4v*)(mL + msw(nbr, quad + 4));
    accu4(v0, acc); accu4(v1, acc + 8);
}

__device__ __forceinline__ void run_k1(const FJob& jb, int g, int h,
                                       bf16* mLDS, bf16* wstage) {
    int t = threadIdx.x;
    const int P = jb.P, nT = jb.nT;
    const int gbase = g * P, nb20 = g * 20;
    int lane = t & 63, wv = t >> 6, quad = lane >> 4, m16 = lane & 15;

    // ---- P0: hs tables via MFMA. Stage all nT tables' W frags (frag-major,
    // coalesced 8-float runs) into mLDS scratch; wave wv<nT computes its table
    // with 32 MFMAs; D stored straight into the swizzled hs layout.
    bf162* hsA = (bf162*)wstage;
    const bf162* hsB = hsA + 1280;
    const bf162* hsC = hsA + 2560;
    bf16* mW = mLDS;   // scratch during P0 (nT*8192 bf16 <= 48KB)
    for (int i = t; i < nT * 8192; i += 1024) {
        int table = i >> 13, r = i & 8191;
        int e = r & 7, mm = (r >> 3) & 15, qq = (r >> 7) & 3;
        int kk = (r >> 9) & 1, mat = (r >> 10) & 1, nn = r >> 11;
        const float* W = mat ? jb.W2t : jb.W1t;
        mW[i] = __float2bfloat16(W[(size_t)(nn * 16 + mm) * jb.ldw + table * 64 + kk * 32 + qq * 8 + e]);
    }
    float* wcT = (float*)(wstage + 7680);   // [2 mats][4 c][64 f]
    if (t < 512) {
        int mat = t >> 8, c = (t >> 6) & 3, f = t & 63;
        const float* W = mat ? jb.wc2 : jb.wc1;
        wcT[mat * 256 + c * 64 + f] = (c < jb.isoC) ? W[f * jb.ldw + c] : 0.f;
    }
    __syncthreads();
    if (wv < nT) {
        const bf16* mWt = mW + wv * 8192;
        bf8v a[2][2];
#pragma unroll
        for (int rt = 0; rt < 2; ++rt) {
            int node = rt * 16 + m16;
#pragma unroll
            for (int kt = 0; kt < 2; ++kt) {
                float tmp[8] = {0.f, 0.f, 0.f, 0.f, 0.f, 0.f, 0.f, 0.f};
                if (node < 20) {
                    const float* hr = jb.hsrc + (size_t)(nb20 + node) * 64 + kt * 32 + quad * 8;
#pragma unroll
                    for (int e = 0; e < 8; ++e) tmp[e] = hr[e];
                }
                a[rt][kt] = pack8(tmp);
            }
        }
        bf162* hsT = hsA + wv * 1280;
#pragma unroll
        for (int n = 0; n < 4; ++n) {
            const bf8v b1k0 = *(const bf8v*)(mWt + ((((n*2+0)*2+0)*4+quad)*16+m16)*8);
            const bf8v b1k1 = *(const bf8v*)(mWt + ((((n*2+0)*2+1)*4+quad)*16+m16)*8);
            const bf8v b2k0 = *(const bf8v*)(mWt + ((((n*2+1)*2+0)*4+quad)*16+m16)*8);
            const bf8v b2k1 = *(const bf8v*)(mWt + ((((n*2+1)*2+1)*4+quad)*16+m16)*8);
#pragma unroll
            for (int rt = 0; rt < 2; ++rt) {
                f4v acca = {0.f, 0.f, 0.f, 0.f};
                f4v accb = {0.f, 0.f, 0.f, 0.f};
                acca = __builtin_amdgcn_mfma_f32_16x16x32_bf16(a[rt][0], b1k0, acca, 0, 0, 0);
                acca = __builtin_amdgcn_mfma_f32_16x16x32_bf16(a[rt][1], b1k1, acca, 0, 0, 0);
                accb = __builtin_amdgcn_mfma_f32_16x16x32_bf16(a[rt][0], b2k0, accb, 0, 0, 0);
                accb = __builtin_amdgcn_mfma_f32_16x16x32_bf16(a[rt][1], b2k1, accb, 0, 0, 0);
                int col = n * 16 + m16, c4 = col >> 2;
#pragma unroll
                for (int r = 0; r < 4; ++r) {
                    int node = rt * 16 + quad * 4 + r;
                    if (node < 20) {
                        bf162 v; v.x = __float2bfloat16(acca[r]); v.y = __float2bfloat16(accb[r]);
                        hsT[(node << 6) + ((c4 ^ (node & 15)) << 2) + (col & 3)] = v;
                    }
                }
            }
        }
    }
    __syncthreads();

    // ---- P1: layer-0 gather -> z (regs, owned rt only) + m0 (LDS, all rows)
    bf8v z8[3][2];
#pragma unroll
    for (int k = 0; k < 3; ++k) {
        int tile = wv + k * 16;
        if (tile >= jb.ntiles) continue;
#pragma unroll
        for (int rt = 0; rt < 2; ++rt) {
            bool own = (rt == h);
            int row = tile * 32 + rt * 16 + m16;
            float zx[16], zy[16];
#pragma unroll
            for (int j = 0; j < 16; ++j) { zx[j] = 0.f; zy[j] = 0.f; }
            if (row < P) {
                size_t gr = (size_t)gbase + row;
                int na = jb.ga[gr] - nb20;
                int nb = jb.gb[gr] - nb20;
                int nc = 0;
                const float* w1r; const float* w2r; float isw;
                if (nT == 3) {
                    nc = jb.gc[gr] - nb20;
                    float4 iv = ((const float4*)jb.iso)[gr];   // one-hot eye(4)[ec]
                    int ec = (int)(iv.y + 2.f * iv.z + 3.f * iv.w + 0.5f);
                    w1r = wcT + ec * 64; w2r = wcT + 256 + ec * 64; isw = 1.f;
                } else {
                    w1r = wcT; w2r = wcT + 256; isw = jb.iso[gr];
                }
#pragma unroll
                for (int kt = 0; kt < 2; ++kt) {
                    int c4 = kt * 8 + quad * 2;
                    int f0 = kt * 32 + quad * 8;
                    if (own) {
                        hsacc(hsA, na, c4, zx + kt * 8, zy + kt * 8);
                        hsacc(hsB, nb, c4, zx + kt * 8, zy + kt * 8);
                        if (nT == 3) hsacc(hsC, nc, c4, zx + kt * 8, zy + kt * 8);
#pragma unroll
                        for (int e = 0; e < 8; ++e)
                            zx[kt * 8 + e] = fmaf(isw, w1r[f0 + e], zx[kt * 8 + e]);
                    } else {
                        hsaccY(hsA, na, c4, zy + kt * 8);
                        hsaccY(hsB, nb, c4, zy + kt * 8);
                        if (nT == 3) hsaccY(hsC, nc, c4, zy + kt * 8);
                    }
#pragma unroll
                    for (int e = 0; e < 8; ++e)
                        zy[kt * 8 + e] = fmaf(isw, w2r[f0 + e], zy[kt * 8 + e]);
                }
                *(bf8v*)(mLDS + msw(row, quad))     = pack8(zy);
                *(bf8v*)(mLDS + msw(row, quad + 4)) = pack8(zy + 8);
            }
            if (own) { z8[k][0] = pack8(zx); z8[k][1] = pack8(zx + 8); }
        }
    }
    __syncthreads();

    // ---- P2: stage layer-1 W frags (frag-major) + neighsum-1 for owned rows
    for (int i = t; i < 8192; i += 1024) {
        int e = i & 7, mm = (i >> 3) & 15, qq = (i >> 7) & 3;
        int kk = (i >> 9) & 1, mat = (i >> 10) & 1, nn = i >> 11;
        const float* W = mat ? jb.Wl2 : jb.Wl1;
        wstage[i] = __float2bfloat16(W[(nn * 16 + mm) * HID + kk * 32 + qq * 8 + e]);
    }
#pragma unroll
    for (int k = 0; k < 3; ++k) {
        int tile = wv + k * 16;
        if (tile >= jb.ntiles) continue;
        int row = tile * 32 + h * 16 + m16;
        float acc[16];
#pragma unroll
        for (int j = 0; j < 16; ++j) acc[j] = 0.f;
        accu4(asu4(z8[k][0]), acc);
        accu4(asu4(z8[k][1]), acc + 8);
        if (row < P) {
            size_t gr = (size_t)gbase + row;
            int cnt = jb.cnt[gr];
            const u16* cs = jb.csrc + gr * (size_t)jb.pad;
            int kk = 0;
            for (; kk + 4 <= cnt; kk += 4) {
                int n0 = cs[kk], n1 = cs[kk + 1], n2 = cs[kk + 2], n3 = cs[kk + 3];
                naccum(mLDS, n0, quad, acc); naccum(mLDS, n1, quad, acc);
                naccum(mLDS, n2, quad, acc); naccum(mLDS, n3, quad, acc);
            }
            for (; kk < cnt; ++kk) naccum(mLDS, cs[kk], quad, acc);
        }
        z8[k][0] = pack8relu(acc);
        z8[k][1] = pack8relu(acc + 8);
    }
    __syncthreads();

    // ---- P3: dual MFMA GEMM (owned rt only). zc + m1 -> GLOBAL.
#pragma unroll
    for (int k = 0; k < 3; ++k) {
        int tile = wv + k * 16;
        if (tile >= jb.ntiles) continue;
        int j0 = tile * 32;
#pragma unroll
        for (int n = 0; n < 4; ++n) {
            const bf8v b1k0 = *(const bf8v*)(wstage + ((((n*2+0)*2+0)*4+quad)*16+m16)*8);
            const bf8v b1k1 = *(const bf8v*)(wstage + ((((n*2+0)*2+1)*4+quad)*16+m16)*8);
            const bf8v b2k0 = *(const bf8v*)(wstage + ((((n*2+1)*2+0)*4+quad)*16+m16)*8);
            const bf8v b2k1 = *(const bf8v*)(wstage + ((((n*2+1)*2+1)*4+quad)*16+m16)*8);
            f4v acca = {0.f, 0.f, 0.f, 0.f};
            f4v accb = {0.f, 0.f, 0.f, 0.f};
            acca = __builtin_amdgcn_mfma_f32_16x16x32_bf16(z8[k][0], b1k0, acca, 0, 0, 0);
            acca = __builtin_amdgcn_mfma_f32_16x16x32_bf16(z8[k][1], b1k1, acca, 0, 0, 0);
            accb = __builtin_amdgcn_mfma_f32_16x16x32_bf16(z8[k][0], b2k0, accb, 0, 0, 0);
            accb = __builtin_amdgcn_mfma_f32_16x16x32_bf16(z8[k][1], b2k1, accb, 0, 0, 0);
            int col = n * 16 + m16;
#pragma unroll
            for (int r = 0; r < 4; ++r) {
                int row = j0 + h * 16 + quad * 4 + r;
                if (row < P) {
                    jb.zc[((size_t)gbase + row) * HID + col]  = __float2bfloat16(acca[r]);
                    jb.m1g[((size_t)gbase + row) * HID + col] = __float2bfloat16(accb[r]);
                }
            }
        }
    }
}

__global__ __launch_bounds__(1024, 1)
void fused23a_k(FJob j3, FJob j2, float* __restrict__ comb, int G) {
    __shared__ __align__(16) bf16 mLDS[MROWS * HID];   // 145920 B
    __shared__ __align__(16) bf16 wstage[8768];        //  17536 B
    int b = blockIdx.x;
    int g = b >> 1, h = b & 1;
    if (h == 0 && threadIdx.x < 128) comb[g * 192 + 64 + threadIdx.x] = 0.f;
    run_k1(j3, g, h, mLDS, wstage);
    __syncthreads();
    run_k1(j2, g, h, mLDS, wstage);
}

__device__ __forceinline__ void run_k2(const FJob& jb, int g, int h,
                                       bf16* mLDS, float* part, float* comb) {
    int t = threadIdx.x;
    const int P = jb.P;
    const int gbase = g * P;
    int lane = t & 63, wv = t >> 6, quad = lane >> 4, m16 = lane & 15;
    // stage m1 (full graph) global -> LDS, swizzled
    for (int i = t; i < P * 8; i += 1024) {
        int row = i >> 3, ch = i & 7;
        u4v v = *(const u4v*)(jb.m1g + ((size_t)gbase + row) * HID + ch * 8);
        *(u4v*)(mLDS + msw(row, ch)) = v;
    }
    __syncthreads();
    float ps[16];
#pragma unroll
    for (int j = 0; j < 16; ++j) ps[j] = 0.f;
#pragma unroll
    for (int k = 0; k < 3; ++k) {
        int tile = wv + k * 16;
        if (tile >= jb.ntiles) continue;
        int row = tile * 32 + h * 16 + m16;
        if (row < P) {
            float acc[16];
#pragma unroll
            for (int j = 0; j < 16; ++j) acc[j] = 0.f;
            size_t gr = (size_t)gbase + row;
            u4v zc0 = *(const u4v*)(jb.zc + gr * HID + quad * 8);
            u4v zc1 = *(const u4v*)(jb.zc + gr * HID + 32 + quad * 8);
            accu4(zc0, acc); accu4(zc1, acc + 8);
            int cnt = jb.cnt[gr];
            const u16* cs = jb.csrc + gr * (size_t)jb.pad;
            int kk = 0;
            for (; kk + 4 <= cnt; kk += 4) {
                int n0 = cs[kk], n1 = cs[kk + 1], n2 = cs[kk + 2], n3 = cs[kk + 3];
                naccum(mLDS, n0, quad, acc); naccum(mLDS, n1, quad, acc);
                naccum(mLDS, n2, quad, acc); naccum(mLDS, n3, quad, acc);
            }
            for (; kk < cnt; ++kk) naccum(mLDS, cs[kk], quad, acc);
#pragma unroll
            for (int j = 0; j < 16; ++j) ps[j] += fmaxf(acc[j], 0.f);
        }
    }
#pragma unroll
    for (int j = 0; j < 16; ++j) {
        ps[j] += __shfl_xor(ps[j], 1, 64);
        ps[j] += __shfl_xor(ps[j], 2, 64);
        ps[j] += __shfl_xor(ps[j], 4, 64);
        ps[j] += __shfl_xor(ps[j], 8, 64);
    }
    if (m16 == 0) {
#pragma unroll
        for (int kt = 0; kt < 2; ++kt)
#pragma unroll
            for (int e = 0; e < 8; ++e)
                part[wv * 64 + kt * 32 + quad * 8 + e] = ps[kt * 8 + e];
    }
    __syncthreads();
    if (t < 64) {
        float s = 0.f;
#pragma unroll
        for (int w = 0; w < 16; ++w) s += part[w * 64 + t];
        atomicAdd(&comb[g * 192 + jb.comboff + t], s);
    }
    __syncthreads();
}

__global__ __launch_bounds__(1024, 1)
void fused23b_k(FJob j3, FJob j2, float* __restrict__ comb, int G) {
    __shared__ __align__(16) bf16 mLDS[MROWS * HID];
    __shared__ float part[1024];
    int b = blockIdx.x;
    int g = b >> 1, h = b & 1;
    run_k2(j3, g, h, mLDS, part, comb);
    run_k2(j2, g, h, mLDS, part, comb);
}

// -------- classifier
__global__ void classifier_k(const float* __restrict__ comb,
                             const float* __restrict__ cW1, const float* __restrict__ cb1,
                             const float* __restrict__ cW2, const float* __restrict__ cb2,
                             float* __restrict__ out) {
    __shared__ float row[192];
    __shared__ float hid[64];
    int g = blockIdx.x, t = threadIdx.x;
    for (int i = t; i < 192; i += 64) row[i] = comb[g * 192 + i];
    __syncthreads();
    float acc = cb1[t];
#pragma unroll 8
    for (int k = 0; k < 192; ++k) acc += row[k] * cW1[t * 192 + k];
    hid[t] = fmaxf(acc, 0.f);
    __syncthreads();
    if (t < 10) {
        float o = cb2[t];
#pragma unroll
        for (int k = 0; k < 64; ++k) o += hid[k] * cW2[t * 64 + k];
        out[g * 10 + t] = o;
    }
}

static inline int cdiv(long long a, long long b) { return (int)((a + b - 1) / b); }

extern "C" void kernel_launch(void* const* d_in, const int* in_sizes, int n_in,
                              void* d_out, int out_size, void* d_ws, size_t ws_size,
                              hipStream_t stream) {
    const float* x        = (const float*)d_in[0];
    const int*   eidx     = (const int*)d_in[1];
    const int*   gu2      = (const int*)d_in[3];
    const int*   gv2      = (const int*)d_in[4];
    const float* iso2     = (const float*)d_in[5];
    const int*   tedges   = (const int*)d_in[6];
    const int*   ga3      = (const int*)d_in[8];
    const int*   gb3      = (const int*)d_in[9];
    const int*   gc3      = (const int*)d_in[10];
    const float* iso3     = (const float*)d_in[11];
    const int*   hedges   = (const int*)d_in[12];
    const float* g1W1[3]  = {(const float*)d_in[14], (const float*)d_in[16], (const float*)d_in[18]};
    const float* g1W2[3]  = {(const float*)d_in[15], (const float*)d_in[17], (const float*)d_in[19]};
    const float* g2W1_0   = (const float*)d_in[20];
    const float* g2W2_0   = (const float*)d_in[21];
    const float* g2W1_1   = (const float*)d_in[22];
    const float* g2W2_1   = (const float*)d_in[23];
    const float* g3W1_0   = (const float*)d_in[24];
    const float* g3W2_0   = (const float*)d_in[25];
    const float* g3W1_1   = (const float*)d_in[26];
    const float* g3W2_1   = (const float*)d_in[27];
    const float* cW1      = (const float*)d_in[28];
    const float* cb1      = (const float*)d_in[29];
    const float* cW2      = (const float*)d_in[30];
    const float* cb2      = (const float*)d_in[31];
    float* out = (float*)d_out;

    const int N  = in_sizes[0] / 32;       // 2560
    const int E1 = in_sizes[1] / 2;
    const int n2 = in_sizes[3];            // 24320
    const int E2 = in_sizes[6] / 2;
    const int n3 = in_sizes[8];            // 145920
    const int E3 = in_sizes[12] / 2;
    const int G  = out_size / 10;          // 128
    const int per1 = N / G, per2 = n2 / G, per3 = n3 / G;

    // ---- workspace carve-up (~65 MB)
    float* ws = (float*)d_ws;
    size_t off = 0;
    auto alloc = [&](size_t n) { off = (off + 3) & ~(size_t)3; float* p = ws + off; off += n; return p; };
    const size_t NH = (size_t)N * HID;
    float* h0 = alloc(NH);
    bf16* z2c = (bf16*)alloc((size_t)n2 * HID / 2 + 64);
    bf16* z3c = (bf16*)alloc((size_t)n3 * HID / 2 + 64);
    bf16* m2g = (bf16*)alloc((size_t)n2 * HID / 2 + 64);
    bf16* m3g = (bf16*)alloc((size_t)n3 * HID / 2 + 64);
    float* comb = alloc((size_t)G * 192);
    int* iws = (int*)(ws + off);
    size_t ioff = 0;
    auto ialloc = [&](size_t n) { int* p = iws + ioff; ioff += n; return p; };
    int* cur1 = ialloc(N); int* cur2 = ialloc(n2); int* cur3 = ialloc(n3);   // contiguous
    u16* u16ws = (u16*)(iws + ioff);
    size_t uoff = 0;
    auto ualloc = [&](size_t n) { u16* p = u16ws + uoff; uoff += n; return p; };
    u16* csrc1 = ualloc((size_t)N * PAD1);
    u16* csrc2 = ualloc((size_t)n2 * PAD2);
    u16* csrc3 = ualloc((size_t)n3 * PAD3);
    (void)ws_size;

    dim3 B256(256);

    // ---- padded CSR build: zero + fill (2 dispatches)
    int ncnt = N + n2 + n3;
    zero_k<<<cdiv(ncnt, 256), B256, 0, stream>>>(cur1, ncnt);
    int ne1 = cdiv(E1, 256), ne2 = cdiv(E2, 256), ne3 = cdiv(E3, 256);
    fillp_k<<<ne1 + ne2 + ne3, B256, 0, stream>>>(
        eidx, E1, cur1, csrc1, PAD1, per1,
        tedges, E2, cur2, csrc2, PAD2, per2,
        hedges, E3, cur3, csrc3, PAD3, per3, ne1, ne2);

    // ---- level 1 GNN + h write + segsum (round-4 proven structure)
    level1_k<<<G, B256, 0, stream>>>(x, cur1, csrc1,
        g1W1[0], g1W2[0], g1W1[1], g1W2[1], g1W1[2], g1W2[2], h0, comb, per1);

    // ---- levels 2+3: split K1/K2, (graph, half) blocks; hs via MFMA in-block
    {
        FJob j3, j2;
        j3.hsrc = h0; j3.W1t = g3W1_0; j3.W2t = g3W2_0;
        j3.ga = ga3; j3.gb = gb3; j3.gc = gc3;
        j3.iso = iso3; j3.wc1 = g3W1_0 + 192; j3.wc2 = g3W2_0 + 192;
        j3.ldw = 196; j3.isoC = 4; j3.nT = 3;
        j3.Wl1 = g3W1_1; j3.Wl2 = g3W2_1;
        j3.csrc = csrc3; j3.cnt = cur3; j3.pad = PAD3;
        j3.zc = z3c; j3.m1g = m3g;
        j3.P = per3; j3.ntiles = (per3 + 31) >> 5; j3.comboff = 128;

        j2.hsrc = h0; j2.W1t = g2W1_0; j2.W2t = g2W2_0;
        j2.ga = gu2; j2.gb = gv2; j2.gc = nullptr;
        j2.iso = iso2; j2.wc1 = g2W1_0 + 128; j2.wc2 = g2W2_0 + 128;
        j2.ldw = 129; j2.isoC = 1; j2.nT = 2;
        j2.Wl1 = g2W1_1; j2.Wl2 = g2W2_1;
        j2.csrc = csrc2; j2.cnt = cur2; j2.pad = PAD2;
        j2.zc = z2c; j2.m1g = m2g;
        j2.P = per2; j2.ntiles = (per2 + 31) >> 5; j2.comboff = 64;

        fused23a_k<<<2 * G, 1024, 0, stream>>>(j3, j2, comb, G);
        fused23b_k<<<2 * G, 1024, 0, stream>>>(j3, j2, comb, G);
    }

    // ---- classifier
    classifier_k<<<G, 64, 0, stream>>>(comb, cW1, cb1, cW2, cb2, out);
}

// Round 8
// 264.113 us; speedup vs baseline: 1.7150x; 1.0195x over previous
//
#include <hip/hip_runtime.h>
#include <hip/hip_bf16.h>

#define HID 64
#define MROWS 1140   // C(20,3) rows per graph at level 3
#define PAD1 20      // level-1 in-degree <= 19
#define PAD2 40      // level-2 in-degree <= 38
#define PAD3 60      // level-3 in-degree <= 54

typedef __hip_bfloat16  bf16;
typedef __hip_bfloat162 bf162;
typedef unsigned short  u16;
typedef __attribute__((ext_vector_type(8))) short bf8v;
typedef __attribute__((ext_vector_type(4))) float f4v;
typedef __attribute__((ext_vector_type(4))) unsigned int u4v;
__device__ __forceinline__ float bl(bf16 h) { return __bfloat162float(h); }

// ======== padded CSR build: zero + fill ========
__global__ void zero_k(int* p, int n) {
    int i = blockIdx.x * 256 + threadIdx.x;
    if (i < n) p[i] = 0;
}

__global__ void fillp_k(const int* e1, int E1, int* c1, u16* s1, int p1, int P1_,
                        const int* e2, int E2, int* c2, u16* s2, int p2, int P2_,
                        const int* e3, int E3, int* c3, u16* s3, int p3, int P3_,
                        int nb1, int nb2) {
    int b = blockIdx.x;
    const int* edges; int E; int* cur; u16* csrc; int pad; int P; int lb;
    if (b < nb1)            { edges = e1; E = E1; cur = c1; csrc = s1; pad = p1; P = P1_; lb = b; }
    else if (b < nb1 + nb2) { edges = e2; E = E2; cur = c2; csrc = s2; pad = p2; P = P2_; lb = b - nb1; }
    else                    { edges = e3; E = E3; cur = c3; csrc = s3; pad = p3; P = P3_; lb = b - nb1 - nb2; }
    int e = lb * 256 + threadIdx.x;
    if (e >= E) return;
    int d = edges[E + e];
    int slot = atomicAdd(&cur[d], 1);
    if (slot < pad) csrc[(size_t)d * pad + slot] = (u16)(edges[e] % P);   // local id
}

// ======== FUSED level1 + levels 2+3 K1, split across (graph, half) ====
struct FJob {
    const float *W1t, *W2t;         // level-0 weights (full mats, row stride ldw)
    const int *ga, *gb, *gc;        // global node ids per row (gc null => level 2)
    const float *iso;               // level3: float4 one-hot; level2: float
    const float *wc1, *wc2; int ldw, isoC, nT;
    const float *Wl1, *Wl2;         // layer-1 weights [64][64]
    const u16 *csrc; const int *cnt; int pad;   // padded CSR (local ids)
    bf16 *zc; bf16 *m1g;            // layer-1 preact + message scratch (bf16 [n][64])
    int P, ntiles, comboff;
};

__device__ __forceinline__ int msw(int row, int ch) {
    return (row << 6) + ((ch ^ (row & 7)) << 3);
}
__device__ __forceinline__ void accu4(u4v v, float* f) {
#pragma unroll
    for (int i = 0; i < 4; ++i) {
        f[2 * i]     += __uint_as_float(v[i] << 16);
        f[2 * i + 1] += __uint_as_float(v[i] & 0xffff0000u);
    }
}
__device__ __forceinline__ void accxy4(u4v v, float* zx, float* zy) {
#pragma unroll
    for (int i = 0; i < 4; ++i) {
        zx[i] += __uint_as_float(v[i] << 16);
        zy[i] += __uint_as_float(v[i] & 0xffff0000u);
    }
}
__device__ __forceinline__ bf8v pack8(const float* f) {
    bf16 tmp[8];
#pragma unroll
    for (int e = 0; e < 8; ++e) tmp[e] = __float2bfloat16(f[e]);
    bf8v r; __builtin_memcpy(&r, tmp, 16); return r;
}
__device__ __forceinline__ bf8v pack8relu(const float* f) {
    bf16 tmp[8];
#pragma unroll
    for (int e = 0; e < 8; ++e) tmp[e] = __float2bfloat16(fmaxf(f[e], 0.f));
    bf8v r; __builtin_memcpy(&r, tmp, 16); return r;
}
__device__ __forceinline__ u4v asu4(bf8v v) { u4v r; __builtin_memcpy(&r, &v, 16); return r; }
__device__ __forceinline__ void hsacc(const bf162* tb, int nd, int c4, float* zx, float* zy) {
    u4v v0 = *(const u4v*)(tb + (nd << 6) + (((c4    ) ^ (nd & 15)) << 2));
    u4v v1 = *(const u4v*)(tb + (nd << 6) + (((c4 + 1) ^ (nd & 15)) << 2));
    accxy4(v0, zx, zy);
    accxy4(v1, zx + 4, zy + 4);
}
__device__ __forceinline__ void hsaccY(const bf162* tb, int nd, int c4, float* zy) {
    u4v v0 = *(const u4v*)(tb + (nd << 6) + (((c4    ) ^ (nd & 15)) << 2));
    u4v v1 = *(const u4v*)(tb + (nd << 6) + (((c4 + 1) ^ (nd & 15)) << 2));
#pragma unroll
    for (int i = 0; i < 4; ++i) {
        zy[i]     += __uint_as_float(v0[i] & 0xffff0000u);
        zy[4 + i] += __uint_as_float(v1[i] & 0xffff0000u);
    }
}
__device__ __forceinline__ void naccum(const bf16* mL, int nbr, int quad, float* acc) {
    u4v v0 = *(const u4v*)(mL + msw(nbr, quad));
    u4v v1 = *(const u4v*)(mL + msw(nbr, quad + 4));
    accu4(v0, acc); accu4(v1, acc + 8);
}

// hb: level-1 h in LDS, float[20][65] (stride 65 -> conflict-free MFMA-A reads)
__device__ __forceinline__ void run_k1(const FJob& jb, int g, int h,
                                       bf16* mLDS, bf16* wstage, const float* hb) {
    int t = threadIdx.x;
    const int P = jb.P, nT = jb.nT;
    const int gbase = g * P, nb20 = g * 20;
    int lane = t & 63, wv = t >> 6, quad = lane >> 4, m16 = lane & 15;

    // ---- P0: hs tables via MFMA (A from LDS hb; B frags staged in mLDS scratch)
    bf162* hsA = (bf162*)wstage;
    const bf162* hsB = hsA + 1280;
    const bf162* hsC = hsA + 2560;
    bf16* mW = mLDS;   // scratch during P0 (nT*8192 bf16 <= 48KB, below hb region)
    for (int i = t; i < nT * 8192; i += 1024) {
        int table = i >> 13, r = i & 8191;
        int e = r & 7, mm = (r >> 3) & 15, qq = (r >> 7) & 3;
        int kk = (r >> 9) & 1, mat = (r >> 10) & 1, nn = r >> 11;
        const float* W = mat ? jb.W2t : jb.W1t;
        mW[i] = __float2bfloat16(W[(size_t)(nn * 16 + mm) * jb.ldw + table * 64 + kk * 32 + qq * 8 + e]);
    }
    float* wcT = (float*)(wstage + 7680);   // [2 mats][4 c][64 f]
    if (t < 512) {
        int mat = t >> 8, c = (t >> 6) & 3, f = t & 63;
        const float* W = mat ? jb.wc2 : jb.wc1;
        wcT[mat * 256 + c * 64 + f] = (c < jb.isoC) ? W[f * jb.ldw + c] : 0.f;
    }
    __syncthreads();
    if (wv < nT) {
        const bf16* mWt = mW + wv * 8192;
        bf8v a[2][2];
#pragma unroll
        for (int rt = 0; rt < 2; ++rt) {
            int node = rt * 16 + m16;
#pragma unroll
            for (int kt = 0; kt < 2; ++kt) {
                float tmp[8] = {0.f, 0.f, 0.f, 0.f, 0.f, 0.f, 0.f, 0.f};
                if (node < 20) {
                    const float* hr = hb + node * 65 + kt * 32 + quad * 8;
#pragma unroll
                    for (int e = 0; e < 8; ++e) tmp[e] = hr[e];
                }
                a[rt][kt] = pack8(tmp);
            }
        }
        bf162* hsT = hsA + wv * 1280;
#pragma unroll
        for (int n = 0; n < 4; ++n) {
            const bf8v b1k0 = *(const bf8v*)(mWt + ((((n*2+0)*2+0)*4+quad)*16+m16)*8);
            const bf8v b1k1 = *(const bf8v*)(mWt + ((((n*2+0)*2+1)*4+quad)*16+m16)*8);
            const bf8v b2k0 = *(const bf8v*)(mWt + ((((n*2+1)*2+0)*4+quad)*16+m16)*8);
            const bf8v b2k1 = *(const bf8v*)(mWt + ((((n*2+1)*2+1)*4+quad)*16+m16)*8);
#pragma unroll
            for (int rt = 0; rt < 2; ++rt) {
                f4v acca = {0.f, 0.f, 0.f, 0.f};
                f4v accb = {0.f, 0.f, 0.f, 0.f};
                acca = __builtin_amdgcn_mfma_f32_16x16x32_bf16(a[rt][0], b1k0, acca, 0, 0, 0);
                acca = __builtin_amdgcn_mfma_f32_16x16x32_bf16(a[rt][1], b1k1, acca, 0, 0, 0);
                accb = __builtin_amdgcn_mfma_f32_16x16x32_bf16(a[rt][0], b2k0, accb, 0, 0, 0);
                accb = __builtin_amdgcn_mfma_f32_16x16x32_bf16(a[rt][1], b2k1, accb, 0, 0, 0);
                int col = n * 16 + m16, c4 = col >> 2;
#pragma unroll
                for (int r = 0; r < 4; ++r) {
                    int node = rt * 16 + quad * 4 + r;
                    if (node < 20) {
                        bf162 v; v.x = __float2bfloat16(acca[r]); v.y = __float2bfloat16(accb[r]);
                        hsT[(node << 6) + ((c4 ^ (node & 15)) << 2) + (col & 3)] = v;
                    }
                }
            }
        }
    }
    __syncthreads();

    // ---- P1: layer-0 gather -> z (regs, owned rt only) + m0 (LDS, all rows)
    bf8v z8[3][2];
#pragma unroll
    for (int k = 0; k < 3; ++k) {
        int tile = wv + k * 16;
        if (tile >= jb.ntiles) continue;
#pragma unroll
        for (int rt = 0; rt < 2; ++rt) {
            bool own = (rt == h);
            int row = tile * 32 + rt * 16 + m16;
            float zx[16], zy[16];
#pragma unroll
            for (int j = 0; j < 16; ++j) { zx[j] = 0.f; zy[j] = 0.f; }
            if (row < P) {
                size_t gr = (size_t)gbase + row;
                int na = jb.ga[gr] - nb20;
                int nb = jb.gb[gr] - nb20;
                int nc = 0;
                const float* w1r; const float* w2r; float isw;
                if (nT == 3) {
                    nc = jb.gc[gr] - nb20;
                    float4 iv = ((const float4*)jb.iso)[gr];   // one-hot eye(4)[ec]
                    int ec = (int)(iv.y + 2.f * iv.z + 3.f * iv.w + 0.5f);
                    w1r = wcT + ec * 64; w2r = wcT + 256 + ec * 64; isw = 1.f;
                } else {
                    w1r = wcT; w2r = wcT + 256; isw = jb.iso[gr];
                }
#pragma unroll
                for (int kt = 0; kt < 2; ++kt) {
                    int c4 = kt * 8 + quad * 2;
                    int f0 = kt * 32 + quad * 8;
                    if (own) {
                        hsacc(hsA, na, c4, zx + kt * 8, zy + kt * 8);
                        hsacc(hsB, nb, c4, zx + kt * 8, zy + kt * 8);
                        if (nT == 3) hsacc(hsC, nc, c4, zx + kt * 8, zy + kt * 8);
#pragma unroll
                        for (int e = 0; e < 8; ++e)
                            zx[kt * 8 + e] = fmaf(isw, w1r[f0 + e], zx[kt * 8 + e]);
                    } else {
                        hsaccY(hsA, na, c4, zy + kt * 8);
                        hsaccY(hsB, nb, c4, zy + kt * 8);
                        if (nT == 3) hsaccY(hsC, nc, c4, zy + kt * 8);
                    }
#pragma unroll
                    for (int e = 0; e < 8; ++e)
                        zy[kt * 8 + e] = fmaf(isw, w2r[f0 + e], zy[kt * 8 + e]);
                }
                *(bf8v*)(mLDS + msw(row, quad))     = pack8(zy);
                *(bf8v*)(mLDS + msw(row, quad + 4)) = pack8(zy + 8);
            }
            if (own) { z8[k][0] = pack8(zx); z8[k][1] = pack8(zx + 8); }
        }
    }
    __syncthreads();

    // ---- P2: stage layer-1 W frags (frag-major) + neighsum-1 for owned rows
    for (int i = t; i < 8192; i += 1024) {
        int e = i & 7, mm = (i >> 3) & 15, qq = (i >> 7) & 3;
        int kk = (i >> 9) & 1, mat = (i >> 10) & 1, nn = i >> 11;
        const float* W = mat ? jb.Wl2 : jb.Wl1;
        wstage[i] = __float2bfloat16(W[(nn * 16 + mm) * HID + kk * 32 + qq * 8 + e]);
    }
#pragma unroll
    for (int k = 0; k < 3; ++k) {
        int tile = wv + k * 16;
        if (tile >= jb.ntiles) continue;
        int row = tile * 32 + h * 16 + m16;
        float acc[16];
#pragma unroll
        for (int j = 0; j < 16; ++j) acc[j] = 0.f;
        accu4(asu4(z8[k][0]), acc);
        accu4(asu4(z8[k][1]), acc + 8);
        if (row < P) {
            size_t gr = (size_t)gbase + row;
            int cnt = jb.cnt[gr];
            const u16* cs = jb.csrc + gr * (size_t)jb.pad;
            int kk = 0;
            for (; kk + 4 <= cnt; kk += 4) {
                int n0 = cs[kk], n1 = cs[kk + 1], n2 = cs[kk + 2], n3 = cs[kk + 3];
                naccum(mLDS, n0, quad, acc); naccum(mLDS, n1, quad, acc);
                naccum(mLDS, n2, quad, acc); naccum(mLDS, n3, quad, acc);
            }
            for (; kk < cnt; ++kk) naccum(mLDS, cs[kk], quad, acc);
        }
        z8[k][0] = pack8relu(acc);
        z8[k][1] = pack8relu(acc + 8);
    }
    __syncthreads();

    // ---- P3: dual MFMA GEMM (owned rt only). zc + m1 -> GLOBAL.
#pragma unroll
    for (int k = 0; k < 3; ++k) {
        int tile = wv + k * 16;
        if (tile >= jb.ntiles) continue;
        int j0 = tile * 32;
#pragma unroll
        for (int n = 0; n < 4; ++n) {
            const bf8v b1k0 = *(const bf8v*)(wstage + ((((n*2+0)*2+0)*4+quad)*16+m16)*8);
            const bf8v b1k1 = *(const bf8v*)(wstage + ((((n*2+0)*2+1)*4+quad)*16+m16)*8);
            const bf8v b2k0 = *(const bf8v*)(wstage + ((((n*2+1)*2+0)*4+quad)*16+m16)*8);
            const bf8v b2k1 = *(const bf8v*)(wstage + ((((n*2+1)*2+1)*4+quad)*16+m16)*8);
            f4v acca = {0.f, 0.f, 0.f, 0.f};
            f4v accb = {0.f, 0.f, 0.f, 0.f};
            acca = __builtin_amdgcn_mfma_f32_16x16x32_bf16(z8[k][0], b1k0, acca, 0, 0, 0);
            acca = __builtin_amdgcn_mfma_f32_16x16x32_bf16(z8[k][1], b1k1, acca, 0, 0, 0);
            accb = __builtin_amdgcn_mfma_f32_16x16x32_bf16(z8[k][0], b2k0, accb, 0, 0, 0);
            accb = __builtin_amdgcn_mfma_f32_16x16x32_bf16(z8[k][1], b2k1, accb, 0, 0, 0);
            int col = n * 16 + m16;
#pragma unroll
            for (int r = 0; r < 4; ++r) {
                int row = j0 + h * 16 + quad * 4 + r;
                if (row < P) {
                    jb.zc[((size_t)gbase + row) * HID + col]  = __float2bfloat16(acca[r]);
                    jb.m1g[((size_t)gbase + row) * HID + col] = __float2bfloat16(accb[r]);
                }
            }
        }
    }
}

__global__ __launch_bounds__(1024, 1)
void fused23a_k(const float* __restrict__ x,
                const int* __restrict__ cnt1, const u16* __restrict__ csrc1,
                const float* __restrict__ W10, const float* __restrict__ W20,
                const float* __restrict__ W11, const float* __restrict__ W21,
                const float* __restrict__ W12, const float* __restrict__ W22,
                FJob j3, FJob j2, float* __restrict__ comb, int G) {
    __shared__ __align__(16) bf16 mLDS[MROWS * HID];   // 145920 B
    __shared__ __align__(16) bf16 wstage[8768];        //  17536 B
    int b = blockIdx.x, t = threadIdx.x;
    int g = b >> 1, h = b & 1;
    if (h == 0 && t < 128) comb[g * 192 + 64 + t] = 0.f;

    // ---- level-1 prologue (per-block, LDS-only; duplicated across h)
    // hb float[20][65] at mLDS tail; mbuf float[20][64] just below; wl at base.
    float* hb  = (float*)(mLDS + 70360);   // 20*65 floats = 5200 B -> units 70360..72960
    float* mb  = (float*)(mLDS + 67800);   // 20*64 floats = 5120 B
    float* wlA = (float*)mLDS;             // 64*65 floats
    float* wlB = wlA + 64 * 65;            // ends at unit 16640 < 67800
    int col = t & 63, r0 = t >> 6;
    bool has2 = r0 < 4; int r1 = 16 + r0;
    if (t < 640) hb[(t >> 5) * 65 + (t & 31)] = x[(size_t)g * 640 + t];
    const float* W1s[3] = {W10, W11, W12};
    const float* W2s[3] = {W20, W21, W22};
#pragma unroll 1
    for (int l = 0; l < 3; ++l) {
        const int K = l ? 64 : 32, LD = K + 1;
        const float* W1 = W1s[l];
        const float* W2 = W2s[l];
        __syncthreads();
        for (int i = t; i < K * 64; i += 1024) {
            int c = i / K, k = i - c * K;
            wlA[c * LD + k] = W1[i];
            wlB[c * LD + k] = W2[i];
        }
        __syncthreads();
        float az0 = 0.f, am0 = 0.f, az1 = 0.f, am1 = 0.f;
        const float* wr1 = wlA + col * LD;
        const float* wr2 = wlB + col * LD;
        for (int k = 0; k < K; ++k) {
            float w1v = wr1[k], w2v = wr2[k];
            float h0v = hb[r0 * 65 + k];
            az0 = fmaf(h0v, w1v, az0); am0 = fmaf(h0v, w2v, am0);
            if (has2) {
                float h1v = hb[r1 * 65 + k];
                az1 = fmaf(h1v, w1v, az1); am1 = fmaf(h1v, w2v, am1);
            }
        }
        mb[r0 * 64 + col] = am0;
        if (has2) mb[r1 * 64 + col] = am1;
        __syncthreads();
        {
            int cnt = cnt1[g * 20 + r0];
            const u16* cs = csrc1 + (size_t)(g * 20 + r0) * PAD1;
            float acc = az0;
            for (int k = 0; k < cnt; ++k) acc += mb[cs[k] * 64 + col];
            hb[r0 * 65 + col] = fmaxf(acc, 0.f);
        }
        if (has2) {
            int cnt = cnt1[g * 20 + r1];
            const u16* cs = csrc1 + (size_t)(g * 20 + r1) * PAD1;
            float acc = az1;
            for (int k = 0; k < cnt; ++k) acc += mb[cs[k] * 64 + col];
            hb[r1 * 65 + col] = fmaxf(acc, 0.f);
        }
    }
    __syncthreads();
    if (h == 0 && t < 64) {
        float s = 0.f;
#pragma unroll
        for (int r = 0; r < 20; ++r) s += hb[r * 65 + t];
        comb[g * 192 + t] = s;   // level-1 embedding, cols 0..63
    }
    // j2 FIRST: its m0 only touches mLDS rows <190, so hb survives for j3's P0.
    run_k1(j2, g, h, mLDS, wstage, hb);
    __syncthreads();
    run_k1(j3, g, h, mLDS, wstage, hb);
}

__device__ __forceinline__ void run_k2(const FJob& jb, int g, int h,
                                       bf16* mLDS, float* part, float* comb) {
    int t = threadIdx.x;
    const int P = jb.P;
    const int gbase = g * P;
    int lane = t & 63, wv = t >> 6, quad = lane >> 4, m16 = lane & 15;
    // stage m1 (full graph) global -> LDS, swizzled
    for (int i = t; i < P * 8; i += 1024) {
        int row = i >> 3, ch = i & 7;
        u4v v = *(const u4v*)(jb.m1g + ((size_t)gbase + row) * HID + ch * 8);
        *(u4v*)(mLDS + msw(row, ch)) = v;
    }
    __syncthreads();
    float ps[16];
#pragma unroll
    for (int j = 0; j < 16; ++j) ps[j] = 0.f;
#pragma unroll
    for (int k = 0; k < 3; ++k) {
        int tile = wv + k * 16;
        if (tile >= jb.ntiles) continue;
        int row = tile * 32 + h * 16 + m16;
        if (row < P) {
            float acc[16];
#pragma unroll
            for (int j = 0; j < 16; ++j) acc[j] = 0.f;
            size_t gr = (size_t)gbase + row;
            u4v zc0 = *(const u4v*)(jb.zc + gr * HID + quad * 8);
            u4v zc1 = *(const u4v*)(jb.zc + gr * HID + 32 + quad * 8);
            accu4(zc0, acc); accu4(zc1, acc + 8);
            int cnt = jb.cnt[gr];
            const u16* cs = jb.csrc + gr * (size_t)jb.pad;
            int kk = 0;
            for (; kk + 4 <= cnt; kk += 4) {
                int n0 = cs[kk], n1 = cs[kk + 1], n2 = cs[kk + 2], n3 = cs[kk + 3];
                naccum(mLDS, n0, quad, acc); naccum(mLDS, n1, quad, acc);
                naccum(mLDS, n2, quad, acc); naccum(mLDS, n3, quad, acc);
            }
            for (; kk < cnt; ++kk) naccum(mLDS, cs[kk], quad, acc);
#pragma unroll
            for (int j = 0; j < 16; ++j) ps[j] += fmaxf(acc[j], 0.f);
        }
    }
#pragma unroll
    for (int j = 0; j < 16; ++j) {
        ps[j] += __shfl_xor(ps[j], 1, 64);
        ps[j] += __shfl_xor(ps[j], 2, 64);
        ps[j] += __shfl_xor(ps[j], 4, 64);
        ps[j] += __shfl_xor(ps[j], 8, 64);
    }
    if (m16 == 0) {
#pragma unroll
        for (int kt = 0; kt < 2; ++kt)
#pragma unroll
            for (int e = 0; e < 8; ++e)
                part[wv * 64 + kt * 32 + quad * 8 + e] = ps[kt * 8 + e];
    }
    __syncthreads();
    if (t < 64) {
        float s = 0.f;
#pragma unroll
        for (int w = 0; w < 16; ++w) s += part[w * 64 + t];
        atomicAdd(&comb[g * 192 + jb.comboff + t], s);
    }
    __syncthreads();
}

__global__ __launch_bounds__(1024, 1)
void fused23b_k(FJob j3, FJob j2, float* __restrict__ comb, int G) {
    __shared__ __align__(16) bf16 mLDS[MROWS * HID];
    __shared__ float part[1024];
    int b = blockIdx.x;
    int g = b >> 1, h = b & 1;
    run_k2(j3, g, h, mLDS, part, comb);
    run_k2(j2, g, h, mLDS, part, comb);
}

// -------- classifier
__global__ void classifier_k(const float* __restrict__ comb,
                             const float* __restrict__ cW1, const float* __restrict__ cb1,
                             const float* __restrict__ cW2, const float* __restrict__ cb2,
                             float* __restrict__ out) {
    __shared__ float row[192];
    __shared__ float hid[64];
    int g = blockIdx.x, t = threadIdx.x;
    for (int i = t; i < 192; i += 64) row[i] = comb[g * 192 + i];
    __syncthreads();
    float acc = cb1[t];
#pragma unroll 8
    for (int k = 0; k < 192; ++k) acc += row[k] * cW1[t * 192 + k];
    hid[t] = fmaxf(acc, 0.f);
    __syncthreads();
    if (t < 10) {
        float o = cb2[t];
#pragma unroll
        for (int k = 0; k < 64; ++k) o += hid[k] * cW2[t * 64 + k];
        out[g * 10 + t] = o;
    }
}

static inline int cdiv(long long a, long long b) { return (int)((a + b - 1) / b); }

extern "C" void kernel_launch(void* const* d_in, const int* in_sizes, int n_in,
                              void* d_out, int out_size, void* d_ws, size_t ws_size,
                              hipStream_t stream) {
    const float* x        = (const float*)d_in[0];
    const int*   eidx     = (const int*)d_in[1];
    const int*   gu2      = (const int*)d_in[3];
    const int*   gv2      = (const int*)d_in[4];
    const float* iso2     = (const float*)d_in[5];
    const int*   tedges   = (const int*)d_in[6];
    const int*   ga3      = (const int*)d_in[8];
    const int*   gb3      = (const int*)d_in[9];
    const int*   gc3      = (const int*)d_in[10];
    const float* iso3     = (const float*)d_in[11];
    const int*   hedges   = (const int*)d_in[12];
    const float* g1W1[3]  = {(const float*)d_in[14], (const float*)d_in[16], (const float*)d_in[18]};
    const float* g1W2[3]  = {(const float*)d_in[15], (const float*)d_in[17], (const float*)d_in[19]};
    const float* g2W1_0   = (const float*)d_in[20];
    const float* g2W2_0   = (const float*)d_in[21];
    const float* g2W1_1   = (const float*)d_in[22];
    const float* g2W2_1   = (const float*)d_in[23];
    const float* g3W1_0   = (const float*)d_in[24];
    const float* g3W2_0   = (const float*)d_in[25];
    const float* g3W1_1   = (const float*)d_in[26];
    const float* g3W2_1   = (const float*)d_in[27];
    const float* cW1      = (const float*)d_in[28];
    const float* cb1      = (const float*)d_in[29];
    const float* cW2      = (const float*)d_in[30];
    const float* cb2      = (const float*)d_in[31];
    float* out = (float*)d_out;

    const int N  = in_sizes[0] / 32;       // 2560
    const int E1 = in_sizes[1] / 2;
    const int n2 = in_sizes[3];            // 24320
    const int E2 = in_sizes[6] / 2;
    const int n3 = in_sizes[8];            // 145920
    const int E3 = in_sizes[12] / 2;
    const int G  = out_size / 10;          // 128
    const int per1 = N / G, per2 = n2 / G, per3 = n3 / G;

    // ---- workspace carve-up (~64 MB)
    float* ws = (float*)d_ws;
    size_t off = 0;
    auto alloc = [&](size_t n) { off = (off + 3) & ~(size_t)3; float* p = ws + off; off += n; return p; };
    bf16* z2c = (bf16*)alloc((size_t)n2 * HID / 2 + 64);
    bf16* z3c = (bf16*)alloc((size_t)n3 * HID / 2 + 64);
    bf16* m2g = (bf16*)alloc((size_t)n2 * HID / 2 + 64);
    bf16* m3g = (bf16*)alloc((size_t)n3 * HID / 2 + 64);
    float* comb = alloc((size_t)G * 192);
    int* iws = (int*)(ws + off);
    size_t ioff = 0;
    auto ialloc = [&](size_t n) { int* p = iws + ioff; ioff += n; return p; };
    int* cur1 = ialloc(N); int* cur2 = ialloc(n2); int* cur3 = ialloc(n3);   // contiguous
    u16* u16ws = (u16*)(iws + ioff);
    size_t uoff = 0;
    auto ualloc = [&](size_t n) { u16* p = u16ws + uoff; uoff += n; return p; };
    u16* csrc1 = ualloc((size_t)N * PAD1);
    u16* csrc2 = ualloc((size_t)n2 * PAD2);
    u16* csrc3 = ualloc((size_t)n3 * PAD3);
    (void)ws_size;

    dim3 B256(256);

    // ---- padded CSR build: zero + fill (2 dispatches)
    int ncnt = N + n2 + n3;
    zero_k<<<cdiv(ncnt, 256), B256, 0, stream>>>(cur1, ncnt);
    int ne1 = cdiv(E1, 256), ne2 = cdiv(E2, 256), ne3 = cdiv(E3, 256);
    fillp_k<<<ne1 + ne2 + ne3, B256, 0, stream>>>(
        eidx, E1, cur1, csrc1, PAD1, per1,
        tedges, E2, cur2, csrc2, PAD2, per2,
        hedges, E3, cur3, csrc3, PAD3, per3, ne1, ne2);

    // ---- level1 + levels 2+3 K1 fused; then K2; then classifier
    {
        FJob j3, j2;
        j3.W1t = g3W1_0; j3.W2t = g3W2_0;
        j3.ga = ga3; j3.gb = gb3; j3.gc = gc3;
        j3.iso = iso3; j3.wc1 = g3W1_0 + 192; j3.wc2 = g3W2_0 + 192;
        j3.ldw = 196; j3.isoC = 4; j3.nT = 3;
        j3.Wl1 = g3W1_1; j3.Wl2 = g3W2_1;
        j3.csrc = csrc3; j3.cnt = cur3; j3.pad = PAD3;
        j3.zc = z3c; j3.m1g = m3g;
        j3.P = per3; j3.ntiles = (per3 + 31) >> 5; j3.comboff = 128;

        j2.W1t = g2W1_0; j2.W2t = g2W2_0;
        j2.ga = gu2; j2.gb = gv2; j2.gc = nullptr;
        j2.iso = iso2; j2.wc1 = g2W1_0 + 128; j2.wc2 = g2W2_0 + 128;
        j2.ldw = 129; j2.isoC = 1; j2.nT = 2;
        j2.Wl1 = g2W1_1; j2.Wl2 = g2W2_1;
        j2.csrc = csrc2; j2.cnt = cur2; j2.pad = PAD2;
        j2.zc = z2c; j2.m1g = m2g;
        j2.P = per2; j2.ntiles = (per2 + 31) >> 5; j2.comboff = 64;

        fused23a_k<<<2 * G, 1024, 0, stream>>>(x, cur1, csrc1,
            g1W1[0], g1W2[0], g1W1[1], g1W2[1], g1W1[2], g1W2[2], j3, j2, comb, G);
        fused23b_k<<<2 * G, 1024, 0, stream>>>(j3, j2, comb, G);
    }

    // ---- classifier
    classifier_k<<<G, 64, 0, stream>>>(comb, cW1, cb1, cW2, cb2, out);
}

// Round 9
// 263.739 us; speedup vs baseline: 1.7175x; 1.0014x over previous
//
#include <hip/hip_runtime.h>
#include <hip/hip_bf16.h>

#define HID 64
#define MROWS 1140   // C(20,3) rows per graph at level 3
#define PAD1 20      // level-1 in-degree <= 19
#define PAD2 40      // level-2 in-degree <= 38
#define PAD3 60      // level-3 in-degree <= 54

typedef __hip_bfloat16  bf16;
typedef __hip_bfloat162 bf162;
typedef unsigned short  u16;
typedef __attribute__((ext_vector_type(8))) short bf8v;
typedef __attribute__((ext_vector_type(4))) float f4v;
typedef __attribute__((ext_vector_type(4))) unsigned int u4v;
__device__ __forceinline__ float bl(bf16 h) { return __bfloat162float(h); }

// ======== padded CSR build: zero + fill ========
__global__ void zero_k(int* p, int n) {
    int i = blockIdx.x * 256 + threadIdx.x;
    if (i < n) p[i] = 0;
}

__global__ void fillp_k(const int* e1, int E1, int* c1, u16* s1, int p1, int P1_,
                        const int* e2, int E2, int* c2, u16* s2, int p2, int P2_,
                        const int* e3, int E3, int* c3, u16* s3, int p3, int P3_,
                        int nb1, int nb2) {
    int b = blockIdx.x;
    const int* edges; int E; int* cur; u16* csrc; int pad; int P; int lb;
    if (b < nb1)            { edges = e1; E = E1; cur = c1; csrc = s1; pad = p1; P = P1_; lb = b; }
    else if (b < nb1 + nb2) { edges = e2; E = E2; cur = c2; csrc = s2; pad = p2; P = P2_; lb = b - nb1; }
    else                    { edges = e3; E = E3; cur = c3; csrc = s3; pad = p3; P = P3_; lb = b - nb1 - nb2; }
    int e = lb * 256 + threadIdx.x;
    if (e >= E) return;
    int d = edges[E + e];
    int slot = atomicAdd(&cur[d], 1);
    if (slot < pad) csrc[(size_t)d * pad + slot] = (u16)(edges[e] % P);   // local id
}

// ======== FUSED level1 + levels 2+3 K1, split across (graph, half) ====
struct FJob {
    const float *W1t, *W2t;         // level-0 weights (full mats, row stride ldw)
    const int *ga, *gb, *gc;        // global node ids per row (gc null => level 2)
    const float *iso;               // level3: float4 one-hot; level2: float
    const float *wc1, *wc2; int ldw, isoC, nT;
    const float *Wl1, *Wl2;         // layer-1 weights [64][64]
    const u16 *csrc; const int *cnt; int pad;   // padded CSR (local ids)
    bf16 *zc; bf16 *m1g;            // layer-1 preact + message scratch (bf16 [n][64])
    int P, ntiles, comboff;
};

__device__ __forceinline__ int msw(int row, int ch) {
    return (row << 6) + ((ch ^ (row & 7)) << 3);
}
__device__ __forceinline__ void accu4(u4v v, float* f) {
#pragma unroll
    for (int i = 0; i < 4; ++i) {
        f[2 * i]     += __uint_as_float(v[i] << 16);
        f[2 * i + 1] += __uint_as_float(v[i] & 0xffff0000u);
    }
}
__device__ __forceinline__ void accxy4(u4v v, float* zx, float* zy) {
#pragma unroll
    for (int i = 0; i < 4; ++i) {
        zx[i] += __uint_as_float(v[i] << 16);
        zy[i] += __uint_as_float(v[i] & 0xffff0000u);
    }
}
__device__ __forceinline__ bf8v pack8(const float* f) {
    bf16 tmp[8];
#pragma unroll
    for (int e = 0; e < 8; ++e) tmp[e] = __float2bfloat16(f[e]);
    bf8v r; __builtin_memcpy(&r, tmp, 16); return r;
}
__device__ __forceinline__ bf8v pack8relu(const float* f) {
    bf16 tmp[8];
#pragma unroll
    for (int e = 0; e < 8; ++e) tmp[e] = __float2bfloat16(fmaxf(f[e], 0.f));
    bf8v r; __builtin_memcpy(&r, tmp, 16); return r;
}
__device__ __forceinline__ u4v asu4(bf8v v) { u4v r; __builtin_memcpy(&r, &v, 16); return r; }
__device__ __forceinline__ void hsacc(const bf162* tb, int nd, int c4, float* zx, float* zy) {
    u4v v0 = *(const u4v*)(tb + (nd << 6) + (((c4    ) ^ (nd & 15)) << 2));
    u4v v1 = *(const u4v*)(tb + (nd << 6) + (((c4 + 1) ^ (nd & 15)) << 2));
    accxy4(v0, zx, zy);
    accxy4(v1, zx + 4, zy + 4);
}
__device__ __forceinline__ void hsaccY(const bf162* tb, int nd, int c4, float* zy) {
    u4v v0 = *(const u4v*)(tb + (nd << 6) + (((c4    ) ^ (nd & 15)) << 2));
    u4v v1 = *(const u4v*)(tb + (nd << 6) + (((c4 + 1) ^ (nd & 15)) << 2));
#pragma unroll
    for (int i = 0; i < 4; ++i) {
        zy[i]     += __uint_as_float(v0[i] & 0xffff0000u);
        zy[4 + i] += __uint_as_float(v1[i] & 0xffff0000u);
    }
}
__device__ __forceinline__ void naccum(const bf16* mL, int nbr, int quad, float* acc) {
    u4v v0 = *(const u4v*)(mL + msw(nbr, quad));
    u4v v1 = *(const u4v*)(mL + msw(nbr, quad + 4));
    accu4(v0, acc); accu4(v1, acc + 8);
}

// hb: level-1 h in LDS, float[20][65] (stride 65 -> conflict-free MFMA-A reads)
__device__ __forceinline__ void run_k1(const FJob& jb, int g, int h,
                                       bf16* mLDS, bf16* wstage, const float* hb) {
    int t = threadIdx.x;
    const int P = jb.P, nT = jb.nT;
    const int gbase = g * P, nb20 = g * 20;
    int lane = t & 63, wv = t >> 6, quad = lane >> 4, m16 = lane & 15;

    // ---- P0: hs tables via MFMA (A from LDS hb; B frags staged in mLDS scratch)
    bf162* hsA = (bf162*)wstage;
    const bf162* hsB = hsA + 1280;
    const bf162* hsC = hsA + 2560;
    bf16* mW = mLDS;   // scratch during P0 (nT*8192 bf16 <= 48KB, below hb region)
    for (int i = t; i < nT * 8192; i += 1024) {
        int table = i >> 13, r = i & 8191;
        int e = r & 7, mm = (r >> 3) & 15, qq = (r >> 7) & 3;
        int kk = (r >> 9) & 1, mat = (r >> 10) & 1, nn = r >> 11;
        const float* W = mat ? jb.W2t : jb.W1t;
        mW[i] = __float2bfloat16(W[(size_t)(nn * 16 + mm) * jb.ldw + table * 64 + kk * 32 + qq * 8 + e]);
    }
    float* wcT = (float*)(wstage + 7680);   // [2 mats][4 c][64 f]
    if (t < 512) {
        int mat = t >> 8, c = (t >> 6) & 3, f = t & 63;
        const float* W = mat ? jb.wc2 : jb.wc1;
        wcT[mat * 256 + c * 64 + f] = (c < jb.isoC) ? W[f * jb.ldw + c] : 0.f;
    }
    __syncthreads();
    if (wv < nT) {
        const bf16* mWt = mW + wv * 8192;
        bf8v a[2][2];
#pragma unroll
        for (int rt = 0; rt < 2; ++rt) {
            int node = rt * 16 + m16;
#pragma unroll
            for (int kt = 0; kt < 2; ++kt) {
                float tmp[8] = {0.f, 0.f, 0.f, 0.f, 0.f, 0.f, 0.f, 0.f};
                if (node < 20) {
                    const float* hr = hb + node * 65 + kt * 32 + quad * 8;
#pragma unroll
                    for (int e = 0; e < 8; ++e) tmp[e] = hr[e];
                }
                a[rt][kt] = pack8(tmp);
            }
        }
        bf162* hsT = hsA + wv * 1280;
#pragma unroll
        for (int n = 0; n < 4; ++n) {
            const bf8v b1k0 = *(const bf8v*)(mWt + ((((n*2+0)*2+0)*4+quad)*16+m16)*8);
            const bf8v b1k1 = *(const bf8v*)(mWt + ((((n*2+0)*2+1)*4+quad)*16+m16)*8);
            const bf8v b2k0 = *(const bf8v*)(mWt + ((((n*2+1)*2+0)*4+quad)*16+m16)*8);
            const bf8v b2k1 = *(const bf8v*)(mWt + ((((n*2+1)*2+1)*4+quad)*16+m16)*8);
#pragma unroll
            for (int rt = 0; rt < 2; ++rt) {
                f4v acca = {0.f, 0.f, 0.f, 0.f};
                f4v accb = {0.f, 0.f, 0.f, 0.f};
                acca = __builtin_amdgcn_mfma_f32_16x16x32_bf16(a[rt][0], b1k0, acca, 0, 0, 0);
                acca = __builtin_amdgcn_mfma_f32_16x16x32_bf16(a[rt][1], b1k1, acca, 0, 0, 0);
                accb = __builtin_amdgcn_mfma_f32_16x16x32_bf16(a[rt][0], b2k0, accb, 0, 0, 0);
                accb = __builtin_amdgcn_mfma_f32_16x16x32_bf16(a[rt][1], b2k1, accb, 0, 0, 0);
                int col = n * 16 + m16, c4 = col >> 2;
#pragma unroll
                for (int r = 0; r < 4; ++r) {
                    int node = rt * 16 + quad * 4 + r;
                    if (node < 20) {
                        bf162 v; v.x = __float2bfloat16(acca[r]); v.y = __float2bfloat16(accb[r]);
                        hsT[(node << 6) + ((c4 ^ (node & 15)) << 2) + (col & 3)] = v;
                    }
                }
            }
        }
    }
    __syncthreads();

    // ---- P1: layer-0 gather -> z (regs, owned rt only) + m0 (LDS, all rows)
    bf8v z8[3][2];
#pragma unroll
    for (int k = 0; k < 3; ++k) {
        int tile = wv + k * 16;
        if (tile >= jb.ntiles) continue;
#pragma unroll
        for (int rt = 0; rt < 2; ++rt) {
            bool own = (rt == h);
            int row = tile * 32 + rt * 16 + m16;
            float zx[16], zy[16];
#pragma unroll
            for (int j = 0; j < 16; ++j) { zx[j] = 0.f; zy[j] = 0.f; }
            if (row < P) {
                size_t gr = (size_t)gbase + row;
                int na = jb.ga[gr] - nb20;
                int nb = jb.gb[gr] - nb20;
                int nc = 0;
                const float* w1r; const float* w2r; float isw;
                if (nT == 3) {
                    nc = jb.gc[gr] - nb20;
                    float4 iv = ((const float4*)jb.iso)[gr];   // one-hot eye(4)[ec]
                    int ec = (int)(iv.y + 2.f * iv.z + 3.f * iv.w + 0.5f);
                    w1r = wcT + ec * 64; w2r = wcT + 256 + ec * 64; isw = 1.f;
                } else {
                    w1r = wcT; w2r = wcT + 256; isw = jb.iso[gr];
                }
#pragma unroll
                for (int kt = 0; kt < 2; ++kt) {
                    int c4 = kt * 8 + quad * 2;
                    int f0 = kt * 32 + quad * 8;
                    if (own) {
                        hsacc(hsA, na, c4, zx + kt * 8, zy + kt * 8);
                        hsacc(hsB, nb, c4, zx + kt * 8, zy + kt * 8);
                        if (nT == 3) hsacc(hsC, nc, c4, zx + kt * 8, zy + kt * 8);
#pragma unroll
                        for (int e = 0; e < 8; ++e)
                            zx[kt * 8 + e] = fmaf(isw, w1r[f0 + e], zx[kt * 8 + e]);
                    } else {
                        hsaccY(hsA, na, c4, zy + kt * 8);
                        hsaccY(hsB, nb, c4, zy + kt * 8);
                        if (nT == 3) hsaccY(hsC, nc, c4, zy + kt * 8);
                    }
#pragma unroll
                    for (int e = 0; e < 8; ++e)
                        zy[kt * 8 + e] = fmaf(isw, w2r[f0 + e], zy[kt * 8 + e]);
                }
                *(bf8v*)(mLDS + msw(row, quad))     = pack8(zy);
                *(bf8v*)(mLDS + msw(row, quad + 4)) = pack8(zy + 8);
            }
            if (own) { z8[k][0] = pack8(zx); z8[k][1] = pack8(zx + 8); }
        }
    }
    __syncthreads();

    // ---- P2: stage layer-1 W frags (frag-major) + neighsum-1 for owned rows
    for (int i = t; i < 8192; i += 1024) {
        int e = i & 7, mm = (i >> 3) & 15, qq = (i >> 7) & 3;
        int kk = (i >> 9) & 1, mat = (i >> 10) & 1, nn = i >> 11;
        const float* W = mat ? jb.Wl2 : jb.Wl1;
        wstage[i] = __float2bfloat16(W[(nn * 16 + mm) * HID + kk * 32 + qq * 8 + e]);
    }
#pragma unroll
    for (int k = 0; k < 3; ++k) {
        int tile = wv + k * 16;
        if (tile >= jb.ntiles) continue;
        int row = tile * 32 + h * 16 + m16;
        float acc[16];
#pragma unroll
        for (int j = 0; j < 16; ++j) acc[j] = 0.f;
        accu4(asu4(z8[k][0]), acc);
        accu4(asu4(z8[k][1]), acc + 8);
        if (row < P) {
            size_t gr = (size_t)gbase + row;
            int cnt = jb.cnt[gr];
            const u16* cs = jb.csrc + gr * (size_t)jb.pad;
            int kk = 0;
            for (; kk + 4 <= cnt; kk += 4) {
                int n0 = cs[kk], n1 = cs[kk + 1], n2 = cs[kk + 2], n3 = cs[kk + 3];
                naccum(mLDS, n0, quad, acc); naccum(mLDS, n1, quad, acc);
                naccum(mLDS, n2, quad, acc); naccum(mLDS, n3, quad, acc);
            }
            for (; kk < cnt; ++kk) naccum(mLDS, cs[kk], quad, acc);
        }
        z8[k][0] = pack8relu(acc);
        z8[k][1] = pack8relu(acc + 8);
    }
    __syncthreads();

    // ---- P3: dual MFMA GEMM (owned rt only). zc + m1 -> GLOBAL.
#pragma unroll
    for (int k = 0; k < 3; ++k) {
        int tile = wv + k * 16;
        if (tile >= jb.ntiles) continue;
        int j0 = tile * 32;
#pragma unroll
        for (int n = 0; n < 4; ++n) {
            const bf8v b1k0 = *(const bf8v*)(wstage + ((((n*2+0)*2+0)*4+quad)*16+m16)*8);
            const bf8v b1k1 = *(const bf8v*)(wstage + ((((n*2+0)*2+1)*4+quad)*16+m16)*8);
            const bf8v b2k0 = *(const bf8v*)(wstage + ((((n*2+1)*2+0)*4+quad)*16+m16)*8);
            const bf8v b2k1 = *(const bf8v*)(wstage + ((((n*2+1)*2+1)*4+quad)*16+m16)*8);
            f4v acca = {0.f, 0.f, 0.f, 0.f};
            f4v accb = {0.f, 0.f, 0.f, 0.f};
            acca = __builtin_amdgcn_mfma_f32_16x16x32_bf16(z8[k][0], b1k0, acca, 0, 0, 0);
            acca = __builtin_amdgcn_mfma_f32_16x16x32_bf16(z8[k][1], b1k1, acca, 0, 0, 0);
            accb = __builtin_amdgcn_mfma_f32_16x16x32_bf16(z8[k][0], b2k0, accb, 0, 0, 0);
            accb = __builtin_amdgcn_mfma_f32_16x16x32_bf16(z8[k][1], b2k1, accb, 0, 0, 0);
            int col = n * 16 + m16;
#pragma unroll
            for (int r = 0; r < 4; ++r) {
                int row = j0 + h * 16 + quad * 4 + r;
                if (row < P) {
                    jb.zc[((size_t)gbase + row) * HID + col]  = __float2bfloat16(acca[r]);
                    jb.m1g[((size_t)gbase + row) * HID + col] = __float2bfloat16(accb[r]);
                }
            }
        }
    }
}

__global__ __launch_bounds__(1024, 1)
void fused23a_k(const float* __restrict__ x,
                const int* __restrict__ cnt1, const u16* __restrict__ csrc1,
                const float* __restrict__ W10, const float* __restrict__ W20,
                const float* __restrict__ W11, const float* __restrict__ W21,
                const float* __restrict__ W12, const float* __restrict__ W22,
                FJob j3, FJob j2, float* __restrict__ comb, int G) {
    __shared__ __align__(16) bf16 mLDS[MROWS * HID];   // 145920 B
    __shared__ __align__(16) bf16 wstage[8768];        //  17536 B
    int b = blockIdx.x, t = threadIdx.x;
    int g = b >> 1, h = b & 1;
    if (h == 0 && t < 128) comb[g * 192 + 64 + t] = 0.f;

    // ---- level-1 prologue (per-block, LDS-only; duplicated across h).
    // ALL 3 layers' weights staged in ONE coalesced pass (83456 B at mLDS base;
    // dies before run_k1's mW/m0 writes). hb/mb live at the mLDS tail.
    float* hb  = (float*)(mLDS + 70360);   // float[20][65], bytes 140720..145920
    float* mb  = (float*)(mLDS + 67800);   // float[20][64], bytes 135600..140720
    float* w0A = (float*)mLDS;             // 64*33
    float* w0B = w0A + 2112;
    float* w1A = w0B + 2112;               // 64*65
    float* w1B = w1A + 4160;
    float* w2A = w1B + 4160;
    float* w2B = w2A + 4160;               // ends at 20864 floats = 83456 B
    int col = t & 63, r0 = t >> 6;
    bool has2 = r0 < 4; int r1 = 16 + r0;
    if (t < 640) hb[(t >> 5) * 65 + (t & 31)] = x[(size_t)g * 640 + t];
    for (int i = t; i < 20480; i += 1024) {
        if (i < 4096) {
            int mat = i >> 11, r = i & 2047;
            int c = r >> 5, k = r & 31;
            (mat ? w0B : w0A)[c * 33 + k] = (mat ? W20 : W10)[r];
        } else if (i < 12288) {
            int j = i - 4096;
            int mat = j >> 12, r = j & 4095;
            int c = r >> 6, k = r & 63;
            (mat ? w1B : w1A)[c * 65 + k] = (mat ? W21 : W11)[r];
        } else {
            int j = i - 12288;
            int mat = j >> 12, r = j & 4095;
            int c = r >> 6, k = r & 63;
            (mat ? w2B : w2A)[c * 65 + k] = (mat ? W22 : W12)[r];
        }
    }
    __syncthreads();
    const float* wAs[3] = {w0A, w1A, w2A};
    const float* wBs[3] = {w0B, w1B, w2B};
#pragma unroll 1
    for (int l = 0; l < 3; ++l) {
        const int K = l ? 64 : 32, LD = K + 1;
        const float* wr1 = wAs[l] + col * LD;
        const float* wr2 = wBs[l] + col * LD;
        float az0 = 0.f, am0 = 0.f, az1 = 0.f, am1 = 0.f;
        for (int k = 0; k < K; ++k) {
            float w1v = wr1[k], w2v = wr2[k];
            float h0v = hb[r0 * 65 + k];             // wave-broadcast (free)
            az0 = fmaf(h0v, w1v, az0); am0 = fmaf(h0v, w2v, am0);
            if (has2) {
                float h1v = hb[r1 * 65 + k];
                az1 = fmaf(h1v, w1v, az1); am1 = fmaf(h1v, w2v, am1);
            }
        }
        mb[r0 * 64 + col] = am0;
        if (has2) mb[r1 * 64 + col] = am1;
        __syncthreads();
        {
            int cnt = cnt1[g * 20 + r0];
            const u16* cs = csrc1 + (size_t)(g * 20 + r0) * PAD1;
            float acc = az0;
            for (int k = 0; k < cnt; ++k) acc += mb[cs[k] * 64 + col];
            hb[r0 * 65 + col] = fmaxf(acc, 0.f);
        }
        if (has2) {
            int cnt = cnt1[g * 20 + r1];
            const u16* cs = csrc1 + (size_t)(g * 20 + r1) * PAD1;
            float acc = az1;
            for (int k = 0; k < cnt; ++k) acc += mb[cs[k] * 64 + col];
            hb[r1 * 65 + col] = fmaxf(acc, 0.f);
        }
        __syncthreads();
    }
    if (h == 0 && t < 64) {
        float s = 0.f;
#pragma unroll
        for (int r = 0; r < 20; ++r) s += hb[r * 65 + t];
        comb[g * 192 + t] = s;   // level-1 embedding, cols 0..63
    }
    // j2 FIRST: its m0 only touches mLDS rows <190, so hb survives for j3's P0.
    run_k1(j2, g, h, mLDS, wstage, hb);
    __syncthreads();
    run_k1(j3, g, h, mLDS, wstage, hb);
}

__device__ __forceinline__ void run_k2(const FJob& jb, int g, int h,
                                       bf16* mLDS, float* part, float* comb) {
    int t = threadIdx.x;
    const int P = jb.P;
    const int gbase = g * P;
    int lane = t & 63, wv = t >> 6, quad = lane >> 4, m16 = lane & 15;
    // stage m1 (full graph) global -> LDS, swizzled
    for (int i = t; i < P * 8; i += 1024) {
        int row = i >> 3, ch = i & 7;
        u4v v = *(const u4v*)(jb.m1g + ((size_t)gbase + row) * HID + ch * 8);
        *(u4v*)(mLDS + msw(row, ch)) = v;
    }
    __syncthreads();
    float ps[16];
#pragma unroll
    for (int j = 0; j < 16; ++j) ps[j] = 0.f;
#pragma unroll
    for (int k = 0; k < 3; ++k) {
        int tile = wv + k * 16;
        if (tile >= jb.ntiles) continue;
        int row = tile * 32 + h * 16 + m16;
        if (row < P) {
            float acc[16];
#pragma unroll
            for (int j = 0; j < 16; ++j) acc[j] = 0.f;
            size_t gr = (size_t)gbase + row;
            u4v zc0 = *(const u4v*)(jb.zc + gr * HID + quad * 8);
            u4v zc1 = *(const u4v*)(jb.zc + gr * HID + 32 + quad * 8);
            accu4(zc0, acc); accu4(zc1, acc + 8);
            int cnt = jb.cnt[gr];
            const u16* cs = jb.csrc + gr * (size_t)jb.pad;
            int kk = 0;
            for (; kk + 4 <= cnt; kk += 4) {
                int n0 = cs[kk], n1 = cs[kk + 1], n2 = cs[kk + 2], n3 = cs[kk + 3];
                naccum(mLDS, n0, quad, acc); naccum(mLDS, n1, quad, acc);
                naccum(mLDS, n2, quad, acc); naccum(mLDS, n3, quad, acc);
            }
            for (; kk < cnt; ++kk) naccum(mLDS, cs[kk], quad, acc);
#pragma unroll
            for (int j = 0; j < 16; ++j) ps[j] += fmaxf(acc[j], 0.f);
        }
    }
#pragma unroll
    for (int j = 0; j < 16; ++j) {
        ps[j] += __shfl_xor(ps[j], 1, 64);
        ps[j] += __shfl_xor(ps[j], 2, 64);
        ps[j] += __shfl_xor(ps[j], 4, 64);
        ps[j] += __shfl_xor(ps[j], 8, 64);
    }
    if (m16 == 0) {
#pragma unroll
        for (int kt = 0; kt < 2; ++kt)
#pragma unroll
            for (int e = 0; e < 8; ++e)
                part[wv * 64 + kt * 32 + quad * 8 + e] = ps[kt * 8 + e];
    }
    __syncthreads();
    if (t < 64) {
        float s = 0.f;
#pragma unroll
        for (int w = 0; w < 16; ++w) s += part[w * 64 + t];
        atomicAdd(&comb[g * 192 + jb.comboff + t], s);
    }
    __syncthreads();
}

__global__ __launch_bounds__(1024, 1)
void fused23b_k(FJob j3, FJob j2, float* __restrict__ comb, int G) {
    __shared__ __align__(16) bf16 mLDS[MROWS * HID];
    __shared__ float part[1024];
    int b = blockIdx.x;
    int g = b >> 1, h = b & 1;
    run_k2(j3, g, h, mLDS, part, comb);
    run_k2(j2, g, h, mLDS, part, comb);
}

// -------- classifier
__global__ void classifier_k(const float* __restrict__ comb,
                             const float* __restrict__ cW1, const float* __restrict__ cb1,
                             const float* __restrict__ cW2, const float* __restrict__ cb2,
                             float* __restrict__ out) {
    __shared__ float row[192];
    __shared__ float hid[64];
    int g = blockIdx.x, t = threadIdx.x;
    for (int i = t; i < 192; i += 64) row[i] = comb[g * 192 + i];
    __syncthreads();
    float acc = cb1[t];
#pragma unroll 8
    for (int k = 0; k < 192; ++k) acc += row[k] * cW1[t * 192 + k];
    hid[t] = fmaxf(acc, 0.f);
    __syncthreads();
    if (t < 10) {
        float o = cb2[t];
#pragma unroll
        for (int k = 0; k < 64; ++k) o += hid[k] * cW2[t * 64 + k];
        out[g * 10 + t] = o;
    }
}

static inline int cdiv(long long a, long long b) { return (int)((a + b - 1) / b); }

extern "C" void kernel_launch(void* const* d_in, const int* in_sizes, int n_in,
                              void* d_out, int out_size, void* d_ws, size_t ws_size,
                              hipStream_t stream) {
    const float* x        = (const float*)d_in[0];
    const int*   eidx     = (const int*)d_in[1];
    const int*   gu2      = (const int*)d_in[3];
    const int*   gv2      = (const int*)d_in[4];
    const float* iso2     = (const float*)d_in[5];
    const int*   tedges   = (const int*)d_in[6];
    const int*   ga3      = (const int*)d_in[8];
    const int*   gb3      = (const int*)d_in[9];
    const int*   gc3      = (const int*)d_in[10];
    const float* iso3     = (const float*)d_in[11];
    const int*   hedges   = (const int*)d_in[12];
    const float* g1W1[3]  = {(const float*)d_in[14], (const float*)d_in[16], (const float*)d_in[18]};
    const float* g1W2[3]  = {(const float*)d_in[15], (const float*)d_in[17], (const float*)d_in[19]};
    const float* g2W1_0   = (const float*)d_in[20];
    const float* g2W2_0   = (const float*)d_in[21];
    const float* g2W1_1   = (const float*)d_in[22];
    const float* g2W2_1   = (const float*)d_in[23];
    const float* g3W1_0   = (const float*)d_in[24];
    const float* g3W2_0   = (const float*)d_in[25];
    const float* g3W1_1   = (const float*)d_in[26];
    const float* g3W2_1   = (const float*)d_in[27];
    const float* cW1      = (const float*)d_in[28];
    const float* cb1      = (const float*)d_in[29];
    const float* cW2      = (const float*)d_in[30];
    const float* cb2      = (const float*)d_in[31];
    float* out = (float*)d_out;

    const int N  = in_sizes[0] / 32;       // 2560
    const int E1 = in_sizes[1] / 2;
    const int n2 = in_sizes[3];            // 24320
    const int E2 = in_sizes[6] / 2;
    const int n3 = in_sizes[8];            // 145920
    const int E3 = in_sizes[12] / 2;
    const int G  = out_size / 10;          // 128
    const int per1 = N / G, per2 = n2 / G, per3 = n3 / G;

    // ---- workspace carve-up (~64 MB)
    float* ws = (float*)d_ws;
    size_t off = 0;
    auto alloc = [&](size_t n) { off = (off + 3) & ~(size_t)3; float* p = ws + off; off += n; return p; };
    bf16* z2c = (bf16*)alloc((size_t)n2 * HID / 2 + 64);
    bf16* z3c = (bf16*)alloc((size_t)n3 * HID / 2 + 64);
    bf16* m2g = (bf16*)alloc((size_t)n2 * HID / 2 + 64);
    bf16* m3g = (bf16*)alloc((size_t)n3 * HID / 2 + 64);
    float* comb = alloc((size_t)G * 192);
    int* iws = (int*)(ws + off);
    size_t ioff = 0;
    auto ialloc = [&](size_t n) { int* p = iws + ioff; ioff += n; return p; };
    int* cur1 = ialloc(N); int* cur2 = ialloc(n2); int* cur3 = ialloc(n3);   // contiguous
    u16* u16ws = (u16*)(iws + ioff);
    size_t uoff = 0;
    auto ualloc = [&](size_t n) { u16* p = u16ws + uoff; uoff += n; return p; };
    u16* csrc1 = ualloc((size_t)N * PAD1);
    u16* csrc2 = ualloc((size_t)n2 * PAD2);
    u16* csrc3 = ualloc((size_t)n3 * PAD3);
    (void)ws_size;

    dim3 B256(256);

    // ---- padded CSR build: zero + fill (2 dispatches)
    int ncnt = N + n2 + n3;
    zero_k<<<cdiv(ncnt, 256), B256, 0, stream>>>(cur1, ncnt);
    int ne1 = cdiv(E1, 256), ne2 = cdiv(E2, 256), ne3 = cdiv(E3, 256);
    fillp_k<<<ne1 + ne2 + ne3, B256, 0, stream>>>(
        eidx, E1, cur1, csrc1, PAD1, per1,
        tedges, E2, cur2, csrc2, PAD2, per2,
        hedges, E3, cur3, csrc3, PAD3, per3, ne1, ne2);

    // ---- level1 + levels 2+3 K1 fused; then K2; then classifier
    {
        FJob j3, j2;
        j3.W1t = g3W1_0; j3.W2t = g3W2_0;
        j3.ga = ga3; j3.gb = gb3; j3.gc = gc3;
        j3.iso = iso3; j3.wc1 = g3W1_0 + 192; j3.wc2 = g3W2_0 + 192;
        j3.ldw = 196; j3.isoC = 4; j3.nT = 3;
        j3.Wl1 = g3W1_1; j3.Wl2 = g3W2_1;
        j3.csrc = csrc3; j3.cnt = cur3; j3.pad = PAD3;
        j3.zc = z3c; j3.m1g = m3g;
        j3.P = per3; j3.ntiles = (per3 + 31) >> 5; j3.comboff = 128;

        j2.W1t = g2W1_0; j2.W2t = g2W2_0;
        j2.ga = gu2; j2.gb = gv2; j2.gc = nullptr;
        j2.iso = iso2; j2.wc1 = g2W1_0 + 128; j2.wc2 = g2W2_0 + 128;
        j2.ldw = 129; j2.isoC = 1; j2.nT = 2;
        j2.Wl1 = g2W1_1; j2.Wl2 = g2W2_1;
        j2.csrc = csrc2; j2.cnt = cur2; j2.pad = PAD2;
        j2.zc = z2c; j2.m1g = m2g;
        j2.P = per2; j2.ntiles = (per2 + 31) >> 5; j2.comboff = 64;

        fused23a_k<<<2 * G, 1024, 0, stream>>>(x, cur1, csrc1,
            g1W1[0], g1W2[0], g1W1[1], g1W2[1], g1W1[2], g1W2[2], j3, j2, comb, G);
        fused23b_k<<<2 * G, 1024, 0, stream>>>(j3, j2, comb, G);
    }

    // ---- classifier
    classifier_k<<<G, 64, 0, stream>>>(comb, cW1, cb1, cW2, cb2, out);
}

// Round 10
// 254.036 us; speedup vs baseline: 1.7831x; 1.0382x over previous
//
#include <hip/hip_runtime.h>
#include <hip/hip_bf16.h>

#define HID 64
#define MROWS 1140   // C(20,3) rows per graph at level 3
#define PAD1 20      // level-1 in-degree <= 19
#define PAD2 40      // level-2 in-degree <= 38
#define PAD3 60      // level-3 in-degree <= 54

typedef __hip_bfloat16  bf16;
typedef __hip_bfloat162 bf162;
typedef unsigned short  u16;
typedef __attribute__((ext_vector_type(8))) short bf8v;
typedef __attribute__((ext_vector_type(4))) float f4v;
typedef __attribute__((ext_vector_type(4))) unsigned int u4v;
__device__ __forceinline__ float bl(bf16 h) { return __bfloat162float(h); }

// ======== padded CSR build: zero + fill ========
__global__ void zero_k(int* p, int n) {
    int i = blockIdx.x * 256 + threadIdx.x;
    if (i < n) p[i] = 0;
}

__global__ void fillp_k(const int* e1, int E1, int* c1, u16* s1, int p1, int P1_,
                        const int* e2, int E2, int* c2, u16* s2, int p2, int P2_,
                        const int* e3, int E3, int* c3, u16* s3, int p3, int P3_,
                        int nb1, int nb2) {
    int b = blockIdx.x;
    const int* edges; int E; int* cur; u16* csrc; int pad; int P; int lb;
    if (b < nb1)            { edges = e1; E = E1; cur = c1; csrc = s1; pad = p1; P = P1_; lb = b; }
    else if (b < nb1 + nb2) { edges = e2; E = E2; cur = c2; csrc = s2; pad = p2; P = P2_; lb = b - nb1; }
    else                    { edges = e3; E = E3; cur = c3; csrc = s3; pad = p3; P = P3_; lb = b - nb1 - nb2; }
    int e = lb * 256 + threadIdx.x;
    if (e >= E) return;
    int d = edges[E + e];
    int slot = atomicAdd(&cur[d], 1);
    if (slot < pad) csrc[(size_t)d * pad + slot] = (u16)(edges[e] % P);   // local id
}

// ======== FUSED level1 + levels 2+3 K1, split across (graph, half) ====
struct FJob {
    const float *W1t, *W2t;         // level-0 weights (full mats, row stride ldw)
    const int *ga, *gb, *gc;        // global node ids per row (gc null => level 2)
    const float *iso;               // level3: float4 one-hot; level2: float
    const float *wc1, *wc2; int ldw, isoC, nT;
    const float *Wl1, *Wl2;         // layer-1 weights [64][64]
    const u16 *csrc; const int *cnt; int pad;   // padded CSR (local ids)
    bf16 *zc; bf16 *m1g;            // layer-1 preact + message scratch (bf16 [n][64])
    int P, ntiles, comboff;
};

__device__ __forceinline__ int msw(int row, int ch) {
    return (row << 6) + ((ch ^ (row & 7)) << 3);
}
__device__ __forceinline__ void accu4(u4v v, float* f) {
#pragma unroll
    for (int i = 0; i < 4; ++i) {
        f[2 * i]     += __uint_as_float(v[i] << 16);
        f[2 * i + 1] += __uint_as_float(v[i] & 0xffff0000u);
    }
}
__device__ __forceinline__ void accxy4(u4v v, float* zx, float* zy) {
#pragma unroll
    for (int i = 0; i < 4; ++i) {
        zx[i] += __uint_as_float(v[i] << 16);
        zy[i] += __uint_as_float(v[i] & 0xffff0000u);
    }
}
__device__ __forceinline__ bf8v pack8(const float* f) {
    bf16 tmp[8];
#pragma unroll
    for (int e = 0; e < 8; ++e) tmp[e] = __float2bfloat16(f[e]);
    bf8v r; __builtin_memcpy(&r, tmp, 16); return r;
}
__device__ __forceinline__ bf8v pack8relu(const float* f) {
    bf16 tmp[8];
#pragma unroll
    for (int e = 0; e < 8; ++e) tmp[e] = __float2bfloat16(fmaxf(f[e], 0.f));
    bf8v r; __builtin_memcpy(&r, tmp, 16); return r;
}
__device__ __forceinline__ u4v asu4(bf8v v) { u4v r; __builtin_memcpy(&r, &v, 16); return r; }
__device__ __forceinline__ void hsacc(const bf162* tb, int nd, int c4, float* zx, float* zy) {
    u4v v0 = *(const u4v*)(tb + (nd << 6) + (((c4    ) ^ (nd & 15)) << 2));
    u4v v1 = *(const u4v*)(tb + (nd << 6) + (((c4 + 1) ^ (nd & 15)) << 2));
    accxy4(v0, zx, zy);
    accxy4(v1, zx + 4, zy + 4);
}
__device__ __forceinline__ void hsaccY(const bf162* tb, int nd, int c4, float* zy) {
    u4v v0 = *(const u4v*)(tb + (nd << 6) + (((c4    ) ^ (nd & 15)) << 2));
    u4v v1 = *(const u4v*)(tb + (nd << 6) + (((c4 + 1) ^ (nd & 15)) << 2));
#pragma unroll
    for (int i = 0; i < 4; ++i) {
        zy[i]     += __uint_as_float(v0[i] & 0xffff0000u);
        zy[4 + i] += __uint_as_float(v1[i] & 0xffff0000u);
    }
}
__device__ __forceinline__ void naccum(const bf16* mL, int nbr, int quad, float* acc) {
    u4v v0 = *(const u4v*)(mL + msw(nbr, quad));
    u4v v1 = *(const u4v*)(mL + msw(nbr, quad + 4));
    accu4(v0, acc); accu4(v1, acc + 8);
}

// hb: level-1 h in LDS, float[20][65] (stride 65 -> conflict-free MFMA-A reads)
__device__ __forceinline__ void run_k1(const FJob& jb, int g, int h,
                                       bf16* mLDS, bf16* wstage, const float* hb) {
    int t = threadIdx.x;
    const int P = jb.P, nT = jb.nT;
    const int gbase = g * P, nb20 = g * 20;
    int lane = t & 63, wv = t >> 6, quad = lane >> 4, m16 = lane & 15;

    // ---- P0: hs tables via MFMA (A from LDS hb; B frags staged in mLDS scratch)
    bf162* hsA = (bf162*)wstage;
    const bf162* hsB = hsA + 1280;
    const bf162* hsC = hsA + 2560;
    bf16* mW = mLDS;   // scratch during P0 (nT*8192 bf16 <= 48KB, below hb region)
    for (int i = t; i < nT * 8192; i += 1024) {
        int table = i >> 13, r = i & 8191;
        int e = r & 7, mm = (r >> 3) & 15, qq = (r >> 7) & 3;
        int kk = (r >> 9) & 1, mat = (r >> 10) & 1, nn = r >> 11;
        const float* W = mat ? jb.W2t : jb.W1t;
        mW[i] = __float2bfloat16(W[(size_t)(nn * 16 + mm) * jb.ldw + table * 64 + kk * 32 + qq * 8 + e]);
    }
    float* wcT = (float*)(wstage + 7680);   // [2 mats][4 c][64 f]
    if (t < 512) {
        int mat = t >> 8, c = (t >> 6) & 3, f = t & 63;
        const float* W = mat ? jb.wc2 : jb.wc1;
        wcT[mat * 256 + c * 64 + f] = (c < jb.isoC) ? W[f * jb.ldw + c] : 0.f;
    }
    __syncthreads();
    if (wv < nT) {
        const bf16* mWt = mW + wv * 8192;
        bf8v a[2][2];
#pragma unroll
        for (int rt = 0; rt < 2; ++rt) {
            int node = rt * 16 + m16;
#pragma unroll
            for (int kt = 0; kt < 2; ++kt) {
                float tmp[8] = {0.f, 0.f, 0.f, 0.f, 0.f, 0.f, 0.f, 0.f};
                if (node < 20) {
                    const float* hr = hb + node * 65 + kt * 32 + quad * 8;
#pragma unroll
                    for (int e = 0; e < 8; ++e) tmp[e] = hr[e];
                }
                a[rt][kt] = pack8(tmp);
            }
        }
        bf162* hsT = hsA + wv * 1280;
#pragma unroll
        for (int n = 0; n < 4; ++n) {
            const bf8v b1k0 = *(const bf8v*)(mWt + ((((n*2+0)*2+0)*4+quad)*16+m16)*8);
            const bf8v b1k1 = *(const bf8v*)(mWt + ((((n*2+0)*2+1)*4+quad)*16+m16)*8);
            const bf8v b2k0 = *(const bf8v*)(mWt + ((((n*2+1)*2+0)*4+quad)*16+m16)*8);
            const bf8v b2k1 = *(const bf8v*)(mWt + ((((n*2+1)*2+1)*4+quad)*16+m16)*8);
#pragma unroll
            for (int rt = 0; rt < 2; ++rt) {
                f4v acca = {0.f, 0.f, 0.f, 0.f};
                f4v accb = {0.f, 0.f, 0.f, 0.f};
                acca = __builtin_amdgcn_mfma_f32_16x16x32_bf16(a[rt][0], b1k0, acca, 0, 0, 0);
                acca = __builtin_amdgcn_mfma_f32_16x16x32_bf16(a[rt][1], b1k1, acca, 0, 0, 0);
                accb = __builtin_amdgcn_mfma_f32_16x16x32_bf16(a[rt][0], b2k0, accb, 0, 0, 0);
                accb = __builtin_amdgcn_mfma_f32_16x16x32_bf16(a[rt][1], b2k1, accb, 0, 0, 0);
                int col = n * 16 + m16, c4 = col >> 2;
#pragma unroll
                for (int r = 0; r < 4; ++r) {
                    int node = rt * 16 + quad * 4 + r;
                    if (node < 20) {
                        bf162 v; v.x = __float2bfloat16(acca[r]); v.y = __float2bfloat16(accb[r]);
                        hsT[(node << 6) + ((c4 ^ (node & 15)) << 2) + (col & 3)] = v;
                    }
                }
            }
        }
    }
    __syncthreads();

    // ---- P1: layer-0 gather -> z (regs, owned rt only) + m0 (LDS, all rows)
    bf8v z8[3][2];
#pragma unroll
    for (int k = 0; k < 3; ++k) {
        int tile = wv + k * 16;
        if (tile >= jb.ntiles) continue;
#pragma unroll
        for (int rt = 0; rt < 2; ++rt) {
            bool own = (rt == h);
            int row = tile * 32 + rt * 16 + m16;
            float zx[16], zy[16];
#pragma unroll
            for (int j = 0; j < 16; ++j) { zx[j] = 0.f; zy[j] = 0.f; }
            if (row < P) {
                size_t gr = (size_t)gbase + row;
                int na = jb.ga[gr] - nb20;
                int nb = jb.gb[gr] - nb20;
                int nc = 0;
                const float* w1r; const float* w2r; float isw;
                if (nT == 3) {
                    nc = jb.gc[gr] - nb20;
                    float4 iv = ((const float4*)jb.iso)[gr];   // one-hot eye(4)[ec]
                    int ec = (int)(iv.y + 2.f * iv.z + 3.f * iv.w + 0.5f);
                    w1r = wcT + ec * 64; w2r = wcT + 256 + ec * 64; isw = 1.f;
                } else {
                    w1r = wcT; w2r = wcT + 256; isw = jb.iso[gr];
                }
#pragma unroll
                for (int kt = 0; kt < 2; ++kt) {
                    int c4 = kt * 8 + quad * 2;
                    int f0 = kt * 32 + quad * 8;
                    if (own) {
                        hsacc(hsA, na, c4, zx + kt * 8, zy + kt * 8);
                        hsacc(hsB, nb, c4, zx + kt * 8, zy + kt * 8);
                        if (nT == 3) hsacc(hsC, nc, c4, zx + kt * 8, zy + kt * 8);
#pragma unroll
                        for (int e = 0; e < 8; ++e)
                            zx[kt * 8 + e] = fmaf(isw, w1r[f0 + e], zx[kt * 8 + e]);
                    } else {
                        hsaccY(hsA, na, c4, zy + kt * 8);
                        hsaccY(hsB, nb, c4, zy + kt * 8);
                        if (nT == 3) hsaccY(hsC, nc, c4, zy + kt * 8);
                    }
#pragma unroll
                    for (int e = 0; e < 8; ++e)
                        zy[kt * 8 + e] = fmaf(isw, w2r[f0 + e], zy[kt * 8 + e]);
                }
                *(bf8v*)(mLDS + msw(row, quad))     = pack8(zy);
                *(bf8v*)(mLDS + msw(row, quad + 4)) = pack8(zy + 8);
            }
            if (own) { z8[k][0] = pack8(zx); z8[k][1] = pack8(zx + 8); }
        }
    }
    __syncthreads();

    // ---- P2: stage layer-1 W frags (frag-major) + neighsum-1 for owned rows
    for (int i = t; i < 8192; i += 1024) {
        int e = i & 7, mm = (i >> 3) & 15, qq = (i >> 7) & 3;
        int kk = (i >> 9) & 1, mat = (i >> 10) & 1, nn = i >> 11;
        const float* W = mat ? jb.Wl2 : jb.Wl1;
        wstage[i] = __float2bfloat16(W[(nn * 16 + mm) * HID + kk * 32 + qq * 8 + e]);
    }
#pragma unroll
    for (int k = 0; k < 3; ++k) {
        int tile = wv + k * 16;
        if (tile >= jb.ntiles) continue;
        int row = tile * 32 + h * 16 + m16;
        float acc[16];
#pragma unroll
        for (int j = 0; j < 16; ++j) acc[j] = 0.f;
        accu4(asu4(z8[k][0]), acc);
        accu4(asu4(z8[k][1]), acc + 8);
        if (row < P) {
            size_t gr = (size_t)gbase + row;
            int cnt = jb.cnt[gr];
            const u16* cs = jb.csrc + gr * (size_t)jb.pad;
            int kk = 0;
            for (; kk + 4 <= cnt; kk += 4) {
                int n0 = cs[kk], n1 = cs[kk + 1], n2 = cs[kk + 2], n3 = cs[kk + 3];
                naccum(mLDS, n0, quad, acc); naccum(mLDS, n1, quad, acc);
                naccum(mLDS, n2, quad, acc); naccum(mLDS, n3, quad, acc);
            }
            for (; kk < cnt; ++kk) naccum(mLDS, cs[kk], quad, acc);
        }
        z8[k][0] = pack8relu(acc);
        z8[k][1] = pack8relu(acc + 8);
    }
    __syncthreads();

    // ---- P3: dual MFMA GEMM (owned rt only). zc + m1 -> GLOBAL.
#pragma unroll
    for (int k = 0; k < 3; ++k) {
        int tile = wv + k * 16;
        if (tile >= jb.ntiles) continue;
        int j0 = tile * 32;
#pragma unroll
        for (int n = 0; n < 4; ++n) {
            const bf8v b1k0 = *(const bf8v*)(wstage + ((((n*2+0)*2+0)*4+quad)*16+m16)*8);
            const bf8v b1k1 = *(const bf8v*)(wstage + ((((n*2+0)*2+1)*4+quad)*16+m16)*8);
            const bf8v b2k0 = *(const bf8v*)(wstage + ((((n*2+1)*2+0)*4+quad)*16+m16)*8);
            const bf8v b2k1 = *(const bf8v*)(wstage + ((((n*2+1)*2+1)*4+quad)*16+m16)*8);
            f4v acca = {0.f, 0.f, 0.f, 0.f};
            f4v accb = {0.f, 0.f, 0.f, 0.f};
            acca = __builtin_amdgcn_mfma_f32_16x16x32_bf16(z8[k][0], b1k0, acca, 0, 0, 0);
            acca = __builtin_amdgcn_mfma_f32_16x16x32_bf16(z8[k][1], b1k1, acca, 0, 0, 0);
            accb = __builtin_amdgcn_mfma_f32_16x16x32_bf16(z8[k][0], b2k0, accb, 0, 0, 0);
            accb = __builtin_amdgcn_mfma_f32_16x16x32_bf16(z8[k][1], b2k1, accb, 0, 0, 0);
            int col = n * 16 + m16;
#pragma unroll
            for (int r = 0; r < 4; ++r) {
                int row = j0 + h * 16 + quad * 4 + r;
                if (row < P) {
                    jb.zc[((size_t)gbase + row) * HID + col]  = __float2bfloat16(acca[r]);
                    jb.m1g[((size_t)gbase + row) * HID + col] = __float2bfloat16(accb[r]);
                }
            }
        }
    }
}

__global__ __launch_bounds__(1024, 1)
void fused23a_k(const float* __restrict__ x,
                const int* __restrict__ cnt1, const u16* __restrict__ csrc1,
                const float* __restrict__ W10, const float* __restrict__ W20,
                const float* __restrict__ W11, const float* __restrict__ W21,
                const float* __restrict__ W12, const float* __restrict__ W22,
                FJob j3, FJob j2, float* __restrict__ comb, int G) {
    __shared__ __align__(16) bf16 mLDS[MROWS * HID];   // 145920 B
    __shared__ __align__(16) bf16 wstage[8768];        //  17536 B
    int b = blockIdx.x, t = threadIdx.x;
    int g = b >> 1, h = b & 1;
    if (h == 0 && t < 128) comb[g * 192 + 64 + t] = 0.f;

    // ---- level-1 prologue v2: GEMMs via MFMA (waves 0-1), neighsum by all threads.
    // wf bf16[20480] at mLDS base (frag-major, 3 layers); zb/mb/hb f32 at the tail.
    float* hb = (float*)(mLDS + 70360);    // float[20][65], units 70360..72960
    float* mb = (float*)(mLDS + 67800);    // float[20][64], units 67800..70360
    float* zb = (float*)(mLDS + 65240);    // float[20][64], units 65240..67800
    bf16* wf  = mLDS;                      // bf16[20480] = 40960 B
    int lane = t & 63, wv = t >> 6, quad = lane >> 4, m16 = lane & 15;
    int col = lane, r0 = wv;
    bool has2 = r0 < 4; int r1 = 16 + r0;
    if (t < 640) hb[(t >> 5) * 65 + (t & 31)] = x[(size_t)g * 640 + t];
    for (int i = t; i < 20480; i += 1024) {
        bf16 v;
        if (i < 4096) {                    // layer0: r = nn*1024 + mat*512 + qq*128 + mm*8 + e
            int r = i;
            int e = r & 7, mm = (r >> 3) & 15, qq = (r >> 7) & 3;
            int mat = (r >> 9) & 1, nn = r >> 10;
            const float* W = mat ? W20 : W10;
            v = __float2bfloat16(W[(nn * 16 + mm) * 32 + qq * 8 + e]);
        } else {                           // layers1,2: r = nn*2048 + mat*1024 + kt*512 + qq*128 + mm*8 + e
            int j = i - 4096;
            int l2 = j >> 13, r = j & 8191;
            int e = r & 7, mm = (r >> 3) & 15, qq = (r >> 7) & 3;
            int kt = (r >> 9) & 1, mat = (r >> 10) & 1, nn = r >> 11;
            const float* W = l2 ? (mat ? W22 : W12) : (mat ? W21 : W11);
            v = __float2bfloat16(W[(nn * 16 + mm) * 64 + kt * 32 + qq * 8 + e]);
        }
        wf[i] = v;
    }
    __syncthreads();
#pragma unroll 1
    for (int l = 0; l < 3; ++l) {
        if (wv < 2) {   // wave 0 -> z (mat0), wave 1 -> m (mat1)
            const bf16* wbase = wf + (l == 0 ? 0 : (l == 1 ? 4096 : 12288));
            const int nK = l ? 2 : 1;
            const int lstep = l ? 2048 : 1024;
            const int mstep = l ? 1024 : 512;
            bf8v a[2][2];
#pragma unroll
            for (int rt = 0; rt < 2; ++rt) {
                int node = rt * 16 + m16;
#pragma unroll
                for (int kt = 0; kt < 2; ++kt) {
                    float tmp[8] = {0.f, 0.f, 0.f, 0.f, 0.f, 0.f, 0.f, 0.f};
                    if (node < 20 && kt < nK) {
                        const float* hr = hb + node * 65 + kt * 32 + quad * 8;
#pragma unroll
                        for (int e = 0; e < 8; ++e) tmp[e] = hr[e];
                    }
                    a[rt][kt] = pack8(tmp);
                }
            }
            float* ob = wv ? mb : zb;
#pragma unroll
            for (int n = 0; n < 4; ++n) {
                const bf16* bp = wbase + n * lstep + wv * mstep + (quad * 16 + m16) * 8;
                bf8v b0 = *(const bf8v*)bp;
                bf8v b1 = b0;
                if (l) b1 = *(const bf8v*)(bp + 512);
#pragma unroll
                for (int rt = 0; rt < 2; ++rt) {
                    f4v acc = {0.f, 0.f, 0.f, 0.f};
                    acc = __builtin_amdgcn_mfma_f32_16x16x32_bf16(a[rt][0], b0, acc, 0, 0, 0);
                    if (l) acc = __builtin_amdgcn_mfma_f32_16x16x32_bf16(a[rt][1], b1, acc, 0, 0, 0);
                    int c = n * 16 + m16;
#pragma unroll
                    for (int r = 0; r < 4; ++r) {
                        int row = rt * 16 + quad * 4 + r;
                        if (row < 20) ob[row * 64 + c] = acc[r];
                    }
                }
            }
        }
        __syncthreads();
        {
            float az = zb[r0 * 64 + col];
            int cnt = cnt1[g * 20 + r0];
            const u16* cs = csrc1 + (size_t)(g * 20 + r0) * PAD1;
            for (int k = 0; k < cnt; ++k) az += mb[cs[k] * 64 + col];
            hb[r0 * 65 + col] = fmaxf(az, 0.f);
        }
        if (has2) {
            float az = zb[r1 * 64 + col];
            int cnt = cnt1[g * 20 + r1];
            const u16* cs = csrc1 + (size_t)(g * 20 + r1) * PAD1;
            for (int k = 0; k < cnt; ++k) az += mb[cs[k] * 64 + col];
            hb[r1 * 65 + col] = fmaxf(az, 0.f);
        }
        __syncthreads();
    }
    if (h == 0 && t < 64) {
        float s = 0.f;
#pragma unroll
        for (int r = 0; r < 20; ++r) s += hb[r * 65 + t];
        comb[g * 192 + t] = s;   // level-1 embedding, cols 0..63
    }
    // j2 FIRST: its m0 only touches mLDS rows <190, so hb survives for j3's P0.
    run_k1(j2, g, h, mLDS, wstage, hb);
    __syncthreads();
    run_k1(j3, g, h, mLDS, wstage, hb);
}

__device__ __forceinline__ void run_k2(const FJob& jb, int g, int h,
                                       bf16* mLDS, float* part, float* comb) {
    int t = threadIdx.x;
    const int P = jb.P;
    const int gbase = g * P;
    int lane = t & 63, wv = t >> 6, quad = lane >> 4, m16 = lane & 15;
    // stage m1 (full graph) global -> LDS, swizzled
    for (int i = t; i < P * 8; i += 1024) {
        int row = i >> 3, ch = i & 7;
        u4v v = *(const u4v*)(jb.m1g + ((size_t)gbase + row) * HID + ch * 8);
        *(u4v*)(mLDS + msw(row, ch)) = v;
    }
    __syncthreads();
    float ps[16];
#pragma unroll
    for (int j = 0; j < 16; ++j) ps[j] = 0.f;
#pragma unroll
    for (int k = 0; k < 3; ++k) {
        int tile = wv + k * 16;
        if (tile >= jb.ntiles) continue;
        int row = tile * 32 + h * 16 + m16;
        if (row < P) {
            float acc[16];
#pragma unroll
            for (int j = 0; j < 16; ++j) acc[j] = 0.f;
            size_t gr = (size_t)gbase + row;
            u4v zc0 = *(const u4v*)(jb.zc + gr * HID + quad * 8);
            u4v zc1 = *(const u4v*)(jb.zc + gr * HID + 32 + quad * 8);
            accu4(zc0, acc); accu4(zc1, acc + 8);
            int cnt = jb.cnt[gr];
            const u16* cs = jb.csrc + gr * (size_t)jb.pad;
            int kk = 0;
            for (; kk + 4 <= cnt; kk += 4) {
                int n0 = cs[kk], n1 = cs[kk + 1], n2 = cs[kk + 2], n3 = cs[kk + 3];
                naccum(mLDS, n0, quad, acc); naccum(mLDS, n1, quad, acc);
                naccum(mLDS, n2, quad, acc); naccum(mLDS, n3, quad, acc);
            }
            for (; kk < cnt; ++kk) naccum(mLDS, cs[kk], quad, acc);
#pragma unroll
            for (int j = 0; j < 16; ++j) ps[j] += fmaxf(acc[j], 0.f);
        }
    }
#pragma unroll
    for (int j = 0; j < 16; ++j) {
        ps[j] += __shfl_xor(ps[j], 1, 64);
        ps[j] += __shfl_xor(ps[j], 2, 64);
        ps[j] += __shfl_xor(ps[j], 4, 64);
        ps[j] += __shfl_xor(ps[j], 8, 64);
    }
    if (m16 == 0) {
#pragma unroll
        for (int kt = 0; kt < 2; ++kt)
#pragma unroll
            for (int e = 0; e < 8; ++e)
                part[wv * 64 + kt * 32 + quad * 8 + e] = ps[kt * 8 + e];
    }
    __syncthreads();
    if (t < 64) {
        float s = 0.f;
#pragma unroll
        for (int w = 0; w < 16; ++w) s += part[w * 64 + t];
        atomicAdd(&comb[g * 192 + jb.comboff + t], s);
    }
    __syncthreads();
}

__global__ __launch_bounds__(1024, 1)
void fused23b_k(FJob j3, FJob j2, float* __restrict__ comb, int G) {
    __shared__ __align__(16) bf16 mLDS[MROWS * HID];
    __shared__ float part[1024];
    int b = blockIdx.x;
    int g = b >> 1, h = b & 1;
    run_k2(j3, g, h, mLDS, part, comb);
    run_k2(j2, g, h, mLDS, part, comb);
}

// -------- classifier
__global__ void classifier_k(const float* __restrict__ comb,
                             const float* __restrict__ cW1, const float* __restrict__ cb1,
                             const float* __restrict__ cW2, const float* __restrict__ cb2,
                             float* __restrict__ out) {
    __shared__ float row[192];
    __shared__ float hid[64];
    int g = blockIdx.x, t = threadIdx.x;
    for (int i = t; i < 192; i += 64) row[i] = comb[g * 192 + i];
    __syncthreads();
    float acc = cb1[t];
#pragma unroll 8
    for (int k = 0; k < 192; ++k) acc += row[k] * cW1[t * 192 + k];
    hid[t] = fmaxf(acc, 0.f);
    __syncthreads();
    if (t < 10) {
        float o = cb2[t];
#pragma unroll
        for (int k = 0; k < 64; ++k) o += hid[k] * cW2[t * 64 + k];
        out[g * 10 + t] = o;
    }
}

static inline int cdiv(long long a, long long b) { return (int)((a + b - 1) / b); }

extern "C" void kernel_launch(void* const* d_in, const int* in_sizes, int n_in,
                              void* d_out, int out_size, void* d_ws, size_t ws_size,
                              hipStream_t stream) {
    const float* x        = (const float*)d_in[0];
    const int*   eidx     = (const int*)d_in[1];
    const int*   gu2      = (const int*)d_in[3];
    const int*   gv2      = (const int*)d_in[4];
    const float* iso2     = (const float*)d_in[5];
    const int*   tedges   = (const int*)d_in[6];
    const int*   ga3      = (const int*)d_in[8];
    const int*   gb3      = (const int*)d_in[9];
    const int*   gc3      = (const int*)d_in[10];
    const float* iso3     = (const float*)d_in[11];
    const int*   hedges   = (const int*)d_in[12];
    const float* g1W1[3]  = {(const float*)d_in[14], (const float*)d_in[16], (const float*)d_in[18]};
    const float* g1W2[3]  = {(const float*)d_in[15], (const float*)d_in[17], (const float*)d_in[19]};
    const float* g2W1_0   = (const float*)d_in[20];
    const float* g2W2_0   = (const float*)d_in[21];
    const float* g2W1_1   = (const float*)d_in[22];
    const float* g2W2_1   = (const float*)d_in[23];
    const float* g3W1_0   = (const float*)d_in[24];
    const float* g3W2_0   = (const float*)d_in[25];
    const float* g3W1_1   = (const float*)d_in[26];
    const float* g3W2_1   = (const float*)d_in[27];
    const float* cW1      = (const float*)d_in[28];
    const float* cb1      = (const float*)d_in[29];
    const float* cW2      = (const float*)d_in[30];
    const float* cb2      = (const float*)d_in[31];
    float* out = (float*)d_out;

    const int N  = in_sizes[0] / 32;       // 2560
    const int E1 = in_sizes[1] / 2;
    const int n2 = in_sizes[3];            // 24320
    const int E2 = in_sizes[6] / 2;
    const int n3 = in_sizes[8];            // 145920
    const int E3 = in_sizes[12] / 2;
    const int G  = out_size / 10;          // 128
    const int per1 = N / G, per2 = n2 / G, per3 = n3 / G;

    // ---- workspace carve-up (~64 MB)
    float* ws = (float*)d_ws;
    size_t off = 0;
    auto alloc = [&](size_t n) { off = (off + 3) & ~(size_t)3; float* p = ws + off; off += n; return p; };
    bf16* z2c = (bf16*)alloc((size_t)n2 * HID / 2 + 64);
    bf16* z3c = (bf16*)alloc((size_t)n3 * HID / 2 + 64);
    bf16* m2g = (bf16*)alloc((size_t)n2 * HID / 2 + 64);
    bf16* m3g = (bf16*)alloc((size_t)n3 * HID / 2 + 64);
    float* comb = alloc((size_t)G * 192);
    int* iws = (int*)(ws + off);
    size_t ioff = 0;
    auto ialloc = [&](size_t n) { int* p = iws + ioff; ioff += n; return p; };
    int* cur1 = ialloc(N); int* cur2 = ialloc(n2); int* cur3 = ialloc(n3);   // contiguous
    u16* u16ws = (u16*)(iws + ioff);
    size_t uoff = 0;
    auto ualloc = [&](size_t n) { u16* p = u16ws + uoff; uoff += n; return p; };
    u16* csrc1 = ualloc((size_t)N * PAD1);
    u16* csrc2 = ualloc((size_t)n2 * PAD2);
    u16* csrc3 = ualloc((size_t)n3 * PAD3);
    (void)ws_size;

    dim3 B256(256);

    // ---- padded CSR build: zero + fill (2 dispatches)
    int ncnt = N + n2 + n3;
    zero_k<<<cdiv(ncnt, 256), B256, 0, stream>>>(cur1, ncnt);
    int ne1 = cdiv(E1, 256), ne2 = cdiv(E2, 256), ne3 = cdiv(E3, 256);
    fillp_k<<<ne1 + ne2 + ne3, B256, 0, stream>>>(
        eidx, E1, cur1, csrc1, PAD1, per1,
        tedges, E2, cur2, csrc2, PAD2, per2,
        hedges, E3, cur3, csrc3, PAD3, per3, ne1, ne2);

    // ---- level1 + levels 2+3 K1 fused; then K2; then classifier
    {
        FJob j3, j2;
        j3.W1t = g3W1_0; j3.W2t = g3W2_0;
        j3.ga = ga3; j3.gb = gb3; j3.gc = gc3;
        j3.iso = iso3; j3.wc1 = g3W1_0 + 192; j3.wc2 = g3W2_0 + 192;
        j3.ldw = 196; j3.isoC = 4; j3.nT = 3;
        j3.Wl1 = g3W1_1; j3.Wl2 = g3W2_1;
        j3.csrc = csrc3; j3.cnt = cur3; j3.pad = PAD3;
        j3.zc = z3c; j3.m1g = m3g;
        j3.P = per3; j3.ntiles = (per3 + 31) >> 5; j3.comboff = 128;

        j2.W1t = g2W1_0; j2.W2t = g2W2_0;
        j2.ga = gu2; j2.gb = gv2; j2.gc = nullptr;
        j2.iso = iso2; j2.wc1 = g2W1_0 + 128; j2.wc2 = g2W2_0 + 128;
        j2.ldw = 129; j2.isoC = 1; j2.nT = 2;
        j2.Wl1 = g2W1_1; j2.Wl2 = g2W2_1;
        j2.csrc = csrc2; j2.cnt = cur2; j2.pad = PAD2;
        j2.zc = z2c; j2.m1g = m2g;
        j2.P = per2; j2.ntiles = (per2 + 31) >> 5; j2.comboff = 64;

        fused23a_k<<<2 * G, 1024, 0, stream>>>(x, cur1, csrc1,
            g1W1[0], g1W2[0], g1W1[1], g1W2[1], g1W1[2], g1W2[2], j3, j2, comb, G);
        fused23b_k<<<2 * G, 1024, 0, stream>>>(j3, j2, comb, G);
    }

    // ---- classifier
    classifier_k<<<G, 64, 0, stream>>>(comb, cW1, cb1, cW2, cb2, out);
}